// Round 9
// baseline (3737.318 us; speedup 1.0000x reference)
//
#include <hip/hip_runtime.h>
#include <hip/hip_bf16.h>
#include <math.h>

// Problem constants
#define DEPTH 4
#define D 512
#define H 8
#define DH 64
#define N 1024
#define M 1024
#define V 32000
#define BATCH 2
#define CTXLEN (M + N)         // 2048
#define ROWS (BATCH * N)       // 2048
#define CROWS (BATCH * CTXLEN) // 4096

typedef __hip_bfloat16 bf16;

static __device__ __forceinline__ float b2f(bf16 v) { return __bfloat162float(v); }

// dtype-agnostic load/store: f==1 -> fp32, f==0 -> bf16
static __device__ __forceinline__ float ldf(const void* p, size_t i, int f) {
    return f ? ((const float*)p)[i] : b2f(((const bf16*)p)[i]);
}
static __device__ __forceinline__ void stf(void* p, size_t i, int f, float v) {
    if (f) ((float*)p)[i] = v;
    else   ((bf16*)p)[i] = __float2bfloat16(v);
}
static __device__ __forceinline__ unsigned short f2bits(float v) {
    union { bf16 b; unsigned short u; } cv;
    cv.b = __float2bfloat16(v);
    return cv.u;
}
static __device__ __forceinline__ unsigned short ldbits(const void* p, size_t i, int f) {
    if (f) return f2bits(((const float*)p)[i]);
    return ((const unsigned short*)p)[i];
}
static __device__ __forceinline__ float us2f(unsigned short u) {
    union { float f; unsigned int i; } c;
    c.i = ((unsigned int)u) << 16;
    return c.f;
}
static __device__ __forceinline__ float4 us4f(ushort4 u) {
    float4 r;
    r.x = us2f(u.x); r.y = us2f(u.y); r.z = us2f(u.z); r.w = us2f(u.w);
    return r;
}

// ---------------- dtype detection (device-side, used for data reads) ----------------
__global__ void detect_kernel(const void* __restrict__ p, int* __restrict__ flag,
                              float* __restrict__ aux) {
    __shared__ int cnt;
    if (threadIdx.x == 0) cnt = 0;
    __syncthreads();
    int bad = 0;
    for (int i = threadIdx.x; i < 1024; i += 256) {
        float v = b2f(((const bf16*)p)[i]);
        if (!(fabsf(v) < 16.0f)) bad++;   // NaN also counts as bad
    }
    if (bad) atomicAdd(&cnt, bad);
    __syncthreads();
    if (threadIdx.x == 0) *flag = (cnt >= 8) ? 1 : 0;
    if (threadIdx.x < BATCH) aux[threadIdx.x] = 0.0f;
}

// ---------------- embedding ----------------
__global__ __launch_bounds__(256) void embed_kernel(const int* __restrict__ tokens,
                                                    const void* __restrict__ emb,
                                                    float* __restrict__ x,
                                                    const int* __restrict__ dflag) {
    int f = *dflag;
    int row = blockIdx.x;                 // b*N + i
    int tok = tokens[row];
    float* xr = x + (size_t)row * D;
    for (int d = threadIdx.x; d < D; d += 256)
        xr[d] = ldf(emb, (size_t)tok * D + d, f);
}

// ---------------- sinusoidal embedding table ----------------
__global__ __launch_bounds__(256) void pe_kernel(float* __restrict__ pe) {
    int r = blockIdx.x;
    int k = threadIdx.x;                  // 0..255 (freq index)
    float t = (float)(N - 1 - r);
    float inv = expf(-(float)k * (9.210340371976184f / 256.0f)); // 10000^{-k/256}
    float s = t * inv;
    pe[(size_t)r * D + k]       = sinf(s);
    pe[(size_t)r * D + 256 + k] = cosf(s);
}

// ---------------- expire span gating (per layer) ----------------
__global__ __launch_bounds__(256) void expire_kernel(const void* __restrict__ mems,
                                                     size_t memOff,
                                                     const int* __restrict__ times_l,
                                                     const void* __restrict__ Wexp,
                                                     size_t wOff,
                                                     const void* __restrict__ bexp,
                                                     size_t bOff,
                                                     float* __restrict__ em,
                                                     float* __restrict__ aux,
                                                     const int* __restrict__ dflag) {
    int f = *dflag;
    int wave = (blockIdx.x * 256 + threadIdx.x) >> 6;  // global j over B*M
    int lane = threadIdx.x & 63;
    int b = wave / M, j = wave % M;
    size_t rbase = memOff + ((size_t)b * M + j) * D;
    float s = 0.0f;
    for (int d = lane; d < D; d += 64)
        s += ldf(mems, rbase + d, f) * ldf(Wexp, wOff + d, f);
    #pragma unroll
    for (int off = 32; off > 0; off >>= 1) s += __shfl_xor(s, off, 64);
    if (lane == 0) {
        s += ldf(bexp, bOff, f);
        float e = 1024.0f / (1.0f + expf(-s));      // sigmoid * MAXMEM
        float t = (float)times_l[b * M + j];
        float emv = (e - t) * (1.0f / 128.0f) + 1.0f;
        emv = fminf(fmaxf(emv, 0.0f), 1.0f);
        em[b * M + j] = emv;
        if (emv > 0.0f && emv < 1.0f)
            atomicAdd(&aux[b], e * (1.0f / (128.0f * 1024.0f)));
    }
}

// ---------------- ctx = concat(mem, x) fp32 ----------------
__global__ __launch_bounds__(256) void ctx_kernel(const void* __restrict__ mems,
                                                  size_t memOff,
                                                  const float* __restrict__ x,
                                                  float* __restrict__ ctx,
                                                  const int* __restrict__ dflag) {
    int f = *dflag;
    size_t idx = (size_t)blockIdx.x * 256 + threadIdx.x;  // over B*CTXLEN*D
    int d = idx & (D - 1);
    size_t rowg = idx >> 9;      // /D
    int p = rowg & (CTXLEN - 1);
    int b = rowg >> 11;          // /CTXLEN
    if (p < M) ctx[idx] = ldf(mems, memOff + ((size_t)b * M + p) * D + d, f);
    else       ctx[idx] = x[((size_t)b * N + (p - M)) * D + d];
}

// ---------------- generic tiled VALU GEMM (fp32-exact fallback + tiny pos GEMM) ----------------
#define BM 64
#define BN 64
#define BK 16
__global__ __launch_bounds__(256) void gemm_kernel(int Mm, int Nn, int Kk,
                                                   const float* __restrict__ A,
                                                   const void* __restrict__ Bw, size_t bwOff,
                                                   const void* __restrict__ bias, size_t biasOff,
                                                   float* __restrict__ C,
                                                   void* __restrict__ Cb,
                                                   int epi,
                                                   const int* __restrict__ dflag) {
    int f = *dflag;
    __shared__ __align__(16) float As[BK][BM + 4];
    __shared__ __align__(16) float Bs[BK][BN + 4];
    int tid = threadIdx.x;
    int bm = blockIdx.y * BM;
    int bn = blockIdx.x * BN;
    int tx = tid & 15, ty = tid >> 4;
    int ka = tid & 15, ma = tid >> 4;   // A loads
    int nb = tid & 63, kb = tid >> 6;   // B loads
    float acc[4][4] = {};
    for (int k0 = 0; k0 < Kk; k0 += BK) {
        #pragma unroll
        for (int p = 0; p < 4; ++p)
            As[ka][ma + 16 * p] = A[(size_t)(bm + ma + 16 * p) * Kk + k0 + ka];
        #pragma unroll
        for (int p = 0; p < 4; ++p)
            Bs[kb + 4 * p][nb] = ldf(Bw, bwOff + (size_t)(k0 + kb + 4 * p) * Nn + bn + nb, f);
        __syncthreads();
        #pragma unroll
        for (int k = 0; k < BK; ++k) {
            float4 a4 = *(const float4*)&As[k][ty * 4];
            float4 b4 = *(const float4*)&Bs[k][tx * 4];
            float a[4] = {a4.x, a4.y, a4.z, a4.w};
            float b[4] = {b4.x, b4.y, b4.z, b4.w};
            #pragma unroll
            for (int i = 0; i < 4; ++i)
                #pragma unroll
                for (int j = 0; j < 4; ++j)
                    acc[i][j] += a[i] * b[j];
        }
        __syncthreads();
    }
    #pragma unroll
    for (int i = 0; i < 4; ++i) {
        int row = bm + ty * 4 + i;
        #pragma unroll
        for (int j = 0; j < 4; ++j) {
            int col = bn + tx * 4 + j;
            float v = acc[i][j];
            if (bias) v += ldf(bias, biasOff + col, f);
            size_t idx = (size_t)row * Nn + col;
            if (epi == 2) v = 0.5f * v * (1.0f + erff(v * 0.70710678118654752f));
            if (Cb) { stf(Cb, idx, f, v); }
            else {
                if (epi == 1) v += C[idx];
                C[idx] = v;
            }
        }
    }
}

// ---------------- MFMA bf16 GEMM: C[M,N] = A[M,K](f32 ws) * B[K,N](weights) + bias ----------------
typedef __attribute__((ext_vector_type(8))) short bfrag;   // 8 bf16 (4 VGPRs)
typedef __attribute__((ext_vector_type(4))) float ffrag;   // 4 f32 accum

__global__ __launch_bounds__(256) void mgemm_kernel(int Mm, int Nn, int Kk,
                                                    const float* __restrict__ A,
                                                    const void* __restrict__ Bw, size_t bwOff,
                                                    const void* __restrict__ bias, size_t biasOff,
                                                    float* __restrict__ C,
                                                    void* __restrict__ Cb,
                                                    int epi,
                                                    const int* __restrict__ dflag) {
    int f = *dflag;
    __shared__ __align__(16) unsigned short As[128][48];   // 12 KB
    __shared__ __align__(16) unsigned short Bs[4096];      // 8 KB, frag-ordered [nb][g][c][e]

    int tid = threadIdx.x;
    // XCD-aware block swizzle (T1): bijective remap of flat block id so the 8 XCDs
    // each get a contiguous chunk -> blocks sharing a B-strip stay on one L2.
    // Bijective whenever nwg % 8 == 0 (true for all grids used here: 64/256/4000);
    // correctness-neutral by construction (any bijection just permutes tiles).
    int gx = gridDim.x;
    int nwg = gx * gridDim.y;
    int flat = blockIdx.y * gx + blockIdx.x;
    if ((nwg & 7) == 0) flat = (flat & 7) * (nwg >> 3) + (flat >> 3);
    int bm = (flat % gx) * 128;
    int bn = (flat / gx) * 128;

    // A staging: thread -> (row, 16-wide k half)
    int arow = tid >> 1;
    int akq  = (tid & 1) * 16;
    // wave/lane decomposition
    int wv = tid >> 6;
    int wr = (wv >> 1) * 64;
    int wc = (wv & 1) * 64;
    int lane = tid & 63;
    int lr = lane & 15;
    int lg = lane >> 4;
    int nbBase = wc >> 4;

    ffrag acc[4][4] = {};

    for (int k0 = 0; k0 < Kk; k0 += 32) {
        // ---- stage A (fp32 -> bf16) ----
        const float* Ar = A + (size_t)(bm + arow) * Kk + k0 + akq;
        #pragma unroll
        for (int c = 0; c < 4; ++c) {
            float4 v = *(const float4*)(Ar + 4 * c);
            ushort4 h;
            h.x = f2bits(v.x); h.y = f2bits(v.y); h.z = f2bits(v.z); h.w = f2bits(v.w);
            *(ushort4*)&As[arow][akq + 4 * c] = h;
        }
        // ---- stage B: vectorized along n, scatter to frag order ----
        #pragma unroll
        for (int cc2 = 0; cc2 < 2; ++cc2) {
            int chunk = tid * 2 + cc2;
            int kr = chunk >> 4;              // 0..31
            int cg = chunk & 15;              // col-group of 8
            int colb = cg * 8;
            unsigned short val[8];
            if (f) {
                const float* src = (const float*)Bw + bwOff + (size_t)(k0 + kr) * Nn + bn + colb;
                float4 v0 = *(const float4*)src;
                float4 v1 = *(const float4*)(src + 4);
                val[0] = f2bits(v0.x); val[1] = f2bits(v0.y);
                val[2] = f2bits(v0.z); val[3] = f2bits(v0.w);
                val[4] = f2bits(v1.x); val[5] = f2bits(v1.y);
                val[6] = f2bits(v1.z); val[7] = f2bits(v1.w);
            } else {
                const unsigned short* src = (const unsigned short*)Bw + bwOff
                                          + (size_t)(k0 + kr) * Nn + bn + colb;
                uint4 u = *(const uint4*)src;
                *(uint4*)val = u;
            }
            int g = kr >> 3, ke = kr & 7;
            int base = (((cg >> 1) * 4 + g) * 16 + 8 * (cg & 1));
            #pragma unroll
            for (int j = 0; j < 8; ++j)
                Bs[(base + j) * 8 + ke] = val[j];
        }
        __syncthreads();
        // ---- fragments + MFMA ----
        bfrag af[4], bfv[4];
        #pragma unroll
        for (int m = 0; m < 4; ++m)
            af[m] = *(const bfrag*)&As[wr + m * 16 + lr][lg * 8];
        #pragma unroll
        for (int n = 0; n < 4; ++n)
            bfv[n] = *(const bfrag*)&Bs[(((nbBase + n) * 4 + lg) * 16 + lr) * 8];
        #pragma unroll
        for (int m = 0; m < 4; ++m)
            #pragma unroll
            for (int n = 0; n < 4; ++n)
                acc[m][n] = __builtin_amdgcn_mfma_f32_16x16x32_bf16(af[m], bfv[n], acc[m][n], 0, 0, 0);
        __syncthreads();
    }
    // ---- epilogue: D layout col=lane&15, row=(lane>>4)*4+j ----
    #pragma unroll
    for (int m = 0; m < 4; ++m) {
        int row0 = bm + wr + m * 16 + lg * 4;
        #pragma unroll
        for (int n = 0; n < 4; ++n) {
            int col = bn + wc + n * 16 + lr;
            float bv = bias ? ldf(bias, biasOff + col, f) : 0.0f;
            #pragma unroll
            for (int j = 0; j < 4; ++j) {
                int row = row0 + j;
                float v = acc[m][n][j] + bv;
                size_t idx = (size_t)row * Nn + col;
                if (epi == 2) v = 0.5f * v * (1.0f + erff(v * 0.70710678118654752f));
                if (Cb) { stf(Cb, idx, f, v); }
                else {
                    if (epi == 1) v += C[idx];
                    C[idx] = v;
                }
            }
        }
    }
}

// ---------------- flash-tiled attention (fp32-exact path, AT=32) ----------------
#define AT 32
#define JT 64
__global__ __launch_bounds__(256) void attn_kernel(const float* __restrict__ q,
                                                   const float* __restrict__ kv,
                                                   const float* __restrict__ pos,
                                                   const float* __restrict__ em,
                                                   float* __restrict__ outp) {
    __shared__ __align__(16) float Qs[AT][68];
    __shared__ __align__(16) float KVs[JT][68];
    __shared__ __align__(16) float Ss[AT][65];
    __shared__ __align__(16) float Ps[95][68];
    __shared__ float gates[M];
    __shared__ float mrow[AT], lrow[AT], arow[AT];

    int t = threadIdx.x;
    int bid = blockIdx.x;
    int raw = bid & 31;
    int it = (raw & 1) ? (31 - (raw >> 1)) : (raw >> 1);
    int h = (bid >> 5) & 7;
    int b = bid >> 8;
    int i0 = it * AT;

    for (int idx = t; idx < AT * 64; idx += 256) {
        int il = idx >> 6, d = idx & 63;
        Qs[il][d] = q[((size_t)(b * N + i0 + il)) * D + h * DH + d];
    }
    for (int idx = t; idx < M; idx += 256) gates[idx] = em[b * M + idx];
    if (t < AT) { mrow[t] = -3e38f; lrow[t] = 0.0f; arow[t] = 0.0f; }

    int ti = t >> 4;
    int tj = t & 15;
    float O[2][4] = {};

    int nx = ((i0 + AT - 1) >> 6) + 1;
    int ntiles = M / JT + nx;
    for (int tile = 0; tile < ntiles; ++tile) {
        int t0 = tile * JT;
        int t0x = t0 - M;
        __syncthreads();
        for (int idx = t; idx < JT * 64; idx += 256) {
            int jl = idx >> 6, d = idx & 63;
            KVs[jl][d] = kv[((size_t)(b * CTXLEN + t0 + jl)) * (2 * D) + h * DH + d];
        }
        int r0 = N - 1 - (i0 + AT - 1) + t0x;
        if (t0x >= 0) {
            for (int idx = t; idx < 95 * 64; idx += 256) {
                int w = idx >> 6, d = idx & 63;
                int r = r0 + w; r = r > (N - 1) ? (N - 1) : r;
                Ps[w][d] = pos[(size_t)r * DH + d];
            }
        }
        __syncthreads();
        float s[2][4] = {};
        #pragma unroll
        for (int d4 = 0; d4 < 16; ++d4) {
            float4 qv[2], kv4[4];
            #pragma unroll
            for (int rr = 0; rr < 2; ++rr) qv[rr] = *(const float4*)&Qs[2 * ti + rr][4 * d4];
            #pragma unroll
            for (int cc = 0; cc < 4; ++cc) kv4[cc] = *(const float4*)&KVs[tj + 16 * cc][4 * d4];
            #pragma unroll
            for (int rr = 0; rr < 2; ++rr)
                #pragma unroll
                for (int cc = 0; cc < 4; ++cc)
                    s[rr][cc] += qv[rr].x * kv4[cc].x + qv[rr].y * kv4[cc].y
                               + qv[rr].z * kv4[cc].z + qv[rr].w * kv4[cc].w;
        }
        if (t0x >= 0) {
            #pragma unroll 4
            for (int d4 = 0; d4 < 16; ++d4) {
                float4 qv[2];
                #pragma unroll
                for (int rr = 0; rr < 2; ++rr) qv[rr] = *(const float4*)&Qs[2 * ti + rr][4 * d4];
                #pragma unroll
                for (int rr = 0; rr < 2; ++rr) {
                    int wb = (AT - 1) - (2 * ti + rr);
                    #pragma unroll
                    for (int cc = 0; cc < 4; ++cc) {
                        float4 pv = *(const float4*)&Ps[tj + 16 * cc + wb][4 * d4];
                        s[rr][cc] += qv[rr].x * pv.x + qv[rr].y * pv.y
                                   + qv[rr].z * pv.z + qv[rr].w * pv.w;
                    }
                }
            }
        }
        #pragma unroll
        for (int rr = 0; rr < 2; ++rr) {
            int il = 2 * ti + rr;
            #pragma unroll
            for (int cc = 0; cc < 4; ++cc) {
                int jl = tj + 16 * cc;
                float v = s[rr][cc] * 0.125f;
                if (t0x >= 0 && (t0x + jl) > (i0 + il)) v = -3e38f;
                Ss[il][jl] = v;
            }
        }
        __syncthreads();
        for (int idx = t; idx < JT * 64; idx += 256) {
            int jl = idx >> 6, d = idx & 63;
            KVs[jl][d] = kv[((size_t)(b * CTXLEN + t0 + jl)) * (2 * D) + D + h * DH + d];
        }
        if (t < AT) {
            int il = t;
            float mo = mrow[il];
            float tmax = -3e38f;
            for (int j = 0; j < JT; ++j) tmax = fmaxf(tmax, Ss[il][j]);
            float mn = fmaxf(mo, tmax);
            float alpha = expf(mo - mn);
            float sum = 0.0f;
            for (int j = 0; j < JT; ++j) {
                float e = expf(Ss[il][j] - mn);
                sum += e;
                int jg = t0 + j;
                float g = (jg < M) ? gates[jg] : 1.0f;
                Ss[il][j] = e * g;
            }
            lrow[il] = lrow[il] * alpha + sum;
            mrow[il] = mn;
            arow[il] = alpha;
        }
        __syncthreads();
        float a0 = arow[2 * ti], a1 = arow[2 * ti + 1];
        #pragma unroll
        for (int dd = 0; dd < 4; ++dd) { O[0][dd] *= a0; O[1][dd] *= a1; }
        #pragma unroll
        for (int jb = 0; jb < 16; ++jb) {
            float4 p0 = *(const float4*)&Ss[2 * ti][4 * jb];
            float4 p1 = *(const float4*)&Ss[2 * ti + 1][4 * jb];
            float4 v0 = *(const float4*)&KVs[4 * jb + 0][4 * tj];
            float4 v1 = *(const float4*)&KVs[4 * jb + 1][4 * tj];
            float4 v2 = *(const float4*)&KVs[4 * jb + 2][4 * tj];
            float4 v3 = *(const float4*)&KVs[4 * jb + 3][4 * tj];
            O[0][0] += p0.x * v0.x + p0.y * v1.x + p0.z * v2.x + p0.w * v3.x;
            O[0][1] += p0.x * v0.y + p0.y * v1.y + p0.z * v2.y + p0.w * v3.y;
            O[0][2] += p0.x * v0.z + p0.y * v1.z + p0.z * v2.z + p0.w * v3.z;
            O[0][3] += p0.x * v0.w + p0.y * v1.w + p0.z * v2.w + p0.w * v3.w;
            O[1][0] += p1.x * v0.x + p1.y * v1.x + p1.z * v2.x + p1.w * v3.x;
            O[1][1] += p1.x * v0.y + p1.y * v1.y + p1.z * v2.y + p1.w * v3.y;
            O[1][2] += p1.x * v0.z + p1.y * v1.z + p1.z * v2.z + p1.w * v3.z;
            O[1][3] += p1.x * v0.w + p1.y * v1.w + p1.z * v2.w + p1.w * v3.w;
        }
    }
    #pragma unroll
    for (int rr = 0; rr < 2; ++rr) {
        int il = 2 * ti + rr;
        float inv = 1.0f / lrow[il];
        float4 r4;
        r4.x = O[rr][0] * inv; r4.y = O[rr][1] * inv;
        r4.z = O[rr][2] * inv; r4.w = O[rr][3] * inv;
        *(float4*)&outp[((size_t)(b * N + i0 + il)) * D + h * DH + 4 * tj] = r4;
    }
}

// ---------------- attention v2 (bf16 path): in-wave softmax, 2 barriers/tile, j-split ----------------
// Round-4 harness-passed version: reads fp32 kv, converts to bf16 during staging.
#define JSPLIT 2
__global__ __launch_bounds__(256) void attn2_kernel(const float* __restrict__ q,
                                                    const float* __restrict__ kv,
                                                    const float* __restrict__ pos,
                                                    const float* __restrict__ em,
                                                    float* __restrict__ opart,
                                                    float* __restrict__ mlp) {
    __shared__ __align__(16) float          Qs[AT][68];    // 8704 B
    __shared__ __align__(16) unsigned short Kb[JT][72];    // 9216 B
    __shared__ __align__(16) unsigned short Vb[JT][72];    // 9216 B
    __shared__ __align__(16) float          Pw[AT][68];    // 8704 B
    __shared__ __align__(16) unsigned short Psb[95][72];   // 13680 B
    // total 49520 B -> 3 blocks/CU

    int t = threadIdx.x;
    int bid = blockIdx.x;
    int p   = bid & 1;                 // j-split parity
    int raw = (bid >> 1) & 31;
    int it = (raw & 1) ? (31 - (raw >> 1)) : (raw >> 1);
    int h = (bid >> 6) & 7;
    int b = bid >> 9;
    int i0 = it * AT;

    // stage Q (float4)
    for (int idx = t; idx < AT * 16; idx += 256) {
        int il = idx >> 4, d4 = idx & 15;
        *(float4*)&Qs[il][4 * d4] =
            *(const float4*)&q[((size_t)(b * N + i0 + il)) * D + h * DH + 4 * d4];
    }

    int ti = t >> 4;       // 0..15 -> rows 2ti+rr (16 consecutive lanes per row pair)
    int tj = t & 15;       // S col lane / PV d-chunk
    float O[2][4] = {};
    float mo[2] = {-3e38f, -3e38f};
    float lo[2] = {0.0f, 0.0f};

    int nx = ((i0 + AT - 1) >> 6) + 1;
    int ntiles = M / JT + nx;
    for (int tile = p; tile < ntiles; tile += JSPLIT) {
        int t0 = tile * JT;
        int t0x = t0 - M;
        __syncthreads();                 // prev tile's K/V reads complete
        // ---- stage K and V (bf16, vectorized) ----
        for (int idx = t; idx < JT * 16; idx += 256) {
            int jl = idx >> 4, d4 = idx & 15;
            const float* base = &kv[(size_t)(b * CTXLEN + t0 + jl) * (2 * D) + h * DH + 4 * d4];
            float4 kvv = *(const float4*)base;
            float4 vvv = *(const float4*)(base + D);
            ushort4 ku, vu;
            ku.x = f2bits(kvv.x); ku.y = f2bits(kvv.y); ku.z = f2bits(kvv.z); ku.w = f2bits(kvv.w);
            vu.x = f2bits(vvv.x); vu.y = f2bits(vvv.y); vu.z = f2bits(vvv.z); vu.w = f2bits(vvv.w);
            *(ushort4*)&Kb[jl][4 * d4] = ku;
            *(ushort4*)&Vb[jl][4 * d4] = vu;
        }
        // ---- stage pos window (bf16, vectorized) for x-tiles ----
        if (t0x >= 0) {
            int r0 = N - 1 - (i0 + AT - 1) + t0x;
            for (int idx = t; idx < 95 * 8; idx += 256) {
                int w = idx >> 3, c = idx & 7;
                int r = r0 + w; r = r > (N - 1) ? (N - 1) : r;
                const float* pp = &pos[(size_t)r * DH + 8 * c];
                float4 a = *(const float4*)pp;
                float4 bb = *(const float4*)(pp + 4);
                ushort4 u0, u1;
                u0.x = f2bits(a.x);  u0.y = f2bits(a.y);  u0.z = f2bits(a.z);  u0.w = f2bits(a.w);
                u1.x = f2bits(bb.x); u1.y = f2bits(bb.y); u1.z = f2bits(bb.z); u1.w = f2bits(bb.w);
                *(ushort4*)&Psb[w][8 * c]     = u0;
                *(ushort4*)&Psb[w][8 * c + 4] = u1;
            }
        }
        __syncthreads();                 // K/V/Ps ready
        // ---- S = Q K^T ----
        float s[2][4] = {};
        #pragma unroll
        for (int d4 = 0; d4 < 16; ++d4) {
            float4 q0 = *(const float4*)&Qs[2 * ti][4 * d4];
            float4 q1 = *(const float4*)&Qs[2 * ti + 1][4 * d4];
            #pragma unroll
            for (int cc = 0; cc < 4; ++cc) {
                float4 kf = us4f(*(const ushort4*)&Kb[tj + 16 * cc][4 * d4]);
                s[0][cc] += q0.x * kf.x + q0.y * kf.y + q0.z * kf.z + q0.w * kf.w;
                s[1][cc] += q1.x * kf.x + q1.y * kf.y + q1.z * kf.z + q1.w * kf.w;
            }
        }
        // ---- + pos skew (x-tiles) ----
        if (t0x >= 0) {
            int wb0 = (AT - 1) - 2 * ti;
            int wb1 = wb0 - 1;
            #pragma unroll 4
            for (int d4 = 0; d4 < 16; ++d4) {
                float4 q0 = *(const float4*)&Qs[2 * ti][4 * d4];
                float4 q1 = *(const float4*)&Qs[2 * ti + 1][4 * d4];
                #pragma unroll
                for (int cc = 0; cc < 4; ++cc) {
                    float4 p0 = us4f(*(const ushort4*)&Psb[tj + 16 * cc + wb0][4 * d4]);
                    float4 p1 = us4f(*(const ushort4*)&Psb[tj + 16 * cc + wb1][4 * d4]);
                    s[0][cc] += q0.x * p0.x + q0.y * p0.y + q0.z * p0.z + q0.w * p0.w;
                    s[1][cc] += q1.x * p1.x + q1.y * p1.y + q1.z * p1.z + q1.w * p1.w;
                }
            }
        }
        // ---- scale + causal mask ----
        #pragma unroll
        for (int rr = 0; rr < 2; ++rr) {
            int il = 2 * ti + rr;
            #pragma unroll
            for (int cc = 0; cc < 4; ++cc) {
                float v = s[rr][cc] * 0.125f;
                int jl = tj + 16 * cc;
                if (t0x >= 0 && (t0x + jl) > (i0 + il)) v = -3e38f;
                s[rr][cc] = v;
            }
        }
        // ---- gates (global, L1-broadcast) ----
        float g4[4];
        #pragma unroll
        for (int cc = 0; cc < 4; ++cc) {
            int jg = t0 + tj + 16 * cc;
            g4[cc] = (jg < M) ? em[b * M + jg] : 1.0f;
        }
        // ---- in-wave online softmax (width-16 shuffles; rows live in 16-lane groups) ----
        #pragma unroll
        for (int rr = 0; rr < 2; ++rr) {
            float tmax = fmaxf(fmaxf(s[rr][0], s[rr][1]), fmaxf(s[rr][2], s[rr][3]));
            tmax = fmaxf(tmax, __shfl_xor(tmax, 8, 16));
            tmax = fmaxf(tmax, __shfl_xor(tmax, 4, 16));
            tmax = fmaxf(tmax, __shfl_xor(tmax, 2, 16));
            tmax = fmaxf(tmax, __shfl_xor(tmax, 1, 16));
            float mn = fmaxf(mo[rr], tmax);
            float al = __expf(mo[rr] - mn);
            mo[rr] = mn;
            float sum = 0.0f;
            float pv4[4];
            #pragma unroll
            for (int cc = 0; cc < 4; ++cc) {
                float e = __expf(s[rr][cc] - mn);
                sum += e;
                pv4[cc] = e * g4[cc];
            }
            sum += __shfl_xor(sum, 8, 16);
            sum += __shfl_xor(sum, 4, 16);
            sum += __shfl_xor(sum, 2, 16);
            sum += __shfl_xor(sum, 1, 16);
            lo[rr] = lo[rr] * al + sum;
            #pragma unroll
            for (int dd = 0; dd < 4; ++dd) O[rr][dd] *= al;
            int il = 2 * ti + rr;
            #pragma unroll
            for (int cc = 0; cc < 4; ++cc) Pw[il][tj + 16 * cc] = pv4[cc];
        }
        // ---- PV (P rows written by this wave; wave64 lockstep -> no barrier) ----
        #pragma unroll
        for (int jb = 0; jb < 16; ++jb) {
            float4 p0 = *(const float4*)&Pw[2 * ti][4 * jb];
            float4 p1 = *(const float4*)&Pw[2 * ti + 1][4 * jb];
            float4 v0 = us4f(*(const ushort4*)&Vb[4 * jb + 0][4 * tj]);
            float4 v1 = us4f(*(const ushort4*)&Vb[4 * jb + 1][4 * tj]);
            float4 v2 = us4f(*(const ushort4*)&Vb[4 * jb + 2][4 * tj]);
            float4 v3 = us4f(*(const ushort4*)&Vb[4 * jb + 3][4 * tj]);
            O[0][0] += p0.x * v0.x + p0.y * v1.x + p0.z * v2.x + p0.w * v3.x;
            O[0][1] += p0.x * v0.y + p0.y * v1.y + p0.z * v2.y + p0.w * v3.y;
            O[0][2] += p0.x * v0.z + p0.y * v1.z + p0.z * v2.z + p0.w * v3.z;
            O[0][3] += p0.x * v0.w + p0.y * v1.w + p0.z * v2.w + p0.w * v3.w;
            O[1][0] += p1.x * v0.x + p1.y * v1.x + p1.z * v2.x + p1.w * v3.x;
            O[1][1] += p1.x * v0.y + p1.y * v1.y + p1.z * v2.y + p1.w * v3.y;
            O[1][2] += p1.x * v0.z + p1.y * v1.z + p1.z * v2.z + p1.w * v3.z;
            O[1][3] += p1.x * v0.w + p1.y * v1.w + p1.z * v2.w + p1.w * v3.w;
        }
    }
    // ---- write unnormalized partials + (m,l) ----
    size_t ob = ((size_t)((p * BATCH + b) * H + h) * N + i0) * DH;
    #pragma unroll
    for (int rr = 0; rr < 2; ++rr) {
        int il = 2 * ti + rr;
        float4 r4;
        r4.x = O[rr][0]; r4.y = O[rr][1]; r4.z = O[rr][2]; r4.w = O[rr][3];
        *(float4*)&opart[ob + (size_t)il * DH + 4 * tj] = r4;
        if (tj == 0) {
            size_t mlIdx = (((size_t)(p * BATCH + b) * H + h) * N + i0 + il) * 2;
            mlp[mlIdx]     = mo[rr];
            mlp[mlIdx + 1] = lo[rr];
        }
    }
}

// ---------------- combine j-split partials ----------------
__global__ __launch_bounds__(256) void attn_combine_kernel(const float* __restrict__ opart,
                                                           const float* __restrict__ mlp,
                                                           float* __restrict__ aout) {
    int row = blockIdx.x;            // b*N + i
    int b = row >> 10;
    int i = row & (N - 1);
    for (int d = threadIdx.x; d < D; d += 256) {
        int h = d >> 6, dd = d & 63;
        size_t s0 = ((size_t)(b * H + h) * N + i);
        size_t s1 = ((size_t)((BATCH + b) * H + h) * N + i);
        float m0 = mlp[s0 * 2], l0 = mlp[s0 * 2 + 1];
        float m1 = mlp[s1 * 2], l1 = mlp[s1 * 2 + 1];
        float m = fmaxf(m0, m1);
        float w0 = __expf(m0 - m), w1 = __expf(m1 - m);
        float denom = l0 * w0 + l1 * w1;
        aout[(size_t)row * D + d] = (opart[s0 * DH + dd] * w0 + opart[s1 * DH + dd] * w1) / denom;
    }
}

// ---------------- final layernorm ----------------
__global__ __launch_bounds__(256) void ln_kernel(const float* __restrict__ x,
                                                 const void* __restrict__ g,
                                                 const void* __restrict__ bta,
                                                 float* __restrict__ y,
                                                 const int* __restrict__ dflag) {
    int f = *dflag;
    int row = blockIdx.x;
    const float* xr = x + (size_t)row * D;
    __shared__ float red[4];
    int lane = threadIdx.x & 63, wv = threadIdx.x >> 6;
    float s = 0.0f;
    for (int d = threadIdx.x; d < D; d += 256) s += xr[d];
    #pragma unroll
    for (int off = 32; off > 0; off >>= 1) s += __shfl_xor(s, off, 64);
    if (lane == 0) red[wv] = s;
    __syncthreads();
    float mu = (red[0] + red[1] + red[2] + red[3]) * (1.0f / D);
    __syncthreads();
    float v = 0.0f;
    for (int d = threadIdx.x; d < D; d += 256) { float tt = xr[d] - mu; v += tt * tt; }
    #pragma unroll
    for (int off = 32; off > 0; off >>= 1) v += __shfl_xor(v, off, 64);
    if (lane == 0) red[wv] = v;
    __syncthreads();
    float var = (red[0] + red[1] + red[2] + red[3]) * (1.0f / D);
    float rstd = 1.0f / sqrtf(var + 1e-5f);
    for (int d = threadIdx.x; d < D; d += 256)
        y[(size_t)row * D + d] = (xr[d] - mu) * rstd * ldf(g, d, f) + ldf(bta, d, f);
}

// ---------------- aux write ----------------
__global__ void write_aux_kernel(const float* __restrict__ aux, void* __restrict__ out,
                                 const int* __restrict__ dflag) {
    int f = *dflag;
    if (threadIdx.x < BATCH)
        stf(out, (size_t)ROWS * V + threadIdx.x, f, aux[threadIdx.x]);
}

extern "C" void kernel_launch(void* const* d_in, const int* in_sizes, int n_in,
                              void* d_out, int out_size, void* d_ws, size_t ws_size,
                              hipStream_t stream) {
    (void)n_in; (void)out_size; (void)ws_size;
    const int*  tokens  = (const int*)d_in[0];
    const void* mems    = d_in[1];
    const int*  times   = (const int*)d_in[2];
    const void* tok_emb = d_in[3];
    const void* Wq   = d_in[4];
    const void* bq   = d_in[5];
    const void* Wkv  = d_in[6];
    const void* bkv  = d_in[7];
    const void* Wo   = d_in[8];
    const void* bo   = d_in[9];
    const void* Wpos = d_in[10];
    const void* bpos = d_in[11];
    const void* Wexp = d_in[12];
    const void* bexp = d_in[13];
    const void* W1   = d_in[14];
    const void* b1   = d_in[15];
    const void* W2   = d_in[16];
    const void* b2v  = d_in[17];
    const void* ln_g = d_in[18];
    const void* ln_b = d_in[19];
    const void* Whead= d_in[20];

    float* ws  = (float*)d_ws;
    float* x    = ws;                            // ROWS*D
    float* pe   = x    + (size_t)ROWS * D;       // N*D
    float* ctx  = pe   + (size_t)N * D;          // CROWS*D   (y, opart alias)
    float* kv   = ctx  + (size_t)CROWS * D;      // CROWS*2D  (h1 aliases)
    float* q    = kv   + (size_t)CROWS * 2 * D;  // ROWS*D
    float* pos  = q    + (size_t)ROWS * D;       // N*DH
    float* em   = pos  + (size_t)N * DH;         // B*M
    float* aout = em   + (size_t)BATCH * M;      // ROWS*D
    float* aux  = aout + (size_t)ROWS * D;       // 2 floats + flag
    int*   flag = (int*)(aux + 2);
    float* mlp  = aux + 16;                      // JSPLIT*B*H*N*2 = 65,536 floats
    float* h1   = kv;   // alias
    float* y    = ctx;  // alias
    float* opart = ctx; // alias: CROWS*D == JSPLIT*B*H*N*DH floats; ctx dead during attn

    // Host-side dtype guess from staged byte size of tok_emb (V*D elems).
    int hf32 = (in_sizes && in_sizes[3] >= (int)(V * (size_t)D * 3)) ? 1 : 0;

    detect_kernel<<<1, 256, 0, stream>>>(tok_emb, flag, aux);
    embed_kernel<<<ROWS, 256, 0, stream>>>(tokens, tok_emb, x, flag);
    pe_kernel<<<N, 256, 0, stream>>>(pe);

    for (int l = 0; l < DEPTH; ++l) {
        expire_kernel<<<(BATCH * M) / 4, 256, 0, stream>>>(
            mems, (size_t)l * BATCH * M * D, times + (size_t)l * BATCH * M,
            Wexp, (size_t)l * D, bexp, (size_t)l, em, aux, flag);
        ctx_kernel<<<(BATCH * CTXLEN * D) / 256, 256, 0, stream>>>(
            mems, (size_t)l * BATCH * M * D, x, ctx, flag);
        if (hf32) {
            gemm_kernel<<<dim3(D / BN, ROWS / BM), 256, 0, stream>>>(
                ROWS, D, D, x, Wq, (size_t)l * D * D, bq, (size_t)l * D, q, nullptr, 0, flag);
            gemm_kernel<<<dim3(2 * D / BN, CROWS / BM), 256, 0, stream>>>(
                CROWS, 2 * D, D, ctx, Wkv, (size_t)l * D * 2 * D, bkv, (size_t)l * 2 * D, kv, nullptr, 0, flag);
        } else {
            mgemm_kernel<<<dim3(ROWS / 128, D / 128), 256, 0, stream>>>(
                ROWS, D, D, x, Wq, (size_t)l * D * D, bq, (size_t)l * D, q, nullptr, 0, flag);
            mgemm_kernel<<<dim3(CROWS / 128, 2 * D / 128), 256, 0, stream>>>(
                CROWS, 2 * D, D, ctx, Wkv, (size_t)l * D * 2 * D, bkv, (size_t)l * 2 * D, kv, nullptr, 0, flag);
        }
        gemm_kernel<<<dim3(DH / BN, N / BM), 256, 0, stream>>>(
            N, DH, D, pe, Wpos, (size_t)l * D * DH, bpos, (size_t)l * DH, pos, nullptr, 0, flag);
        if (hf32) {
            attn_kernel<<<BATCH * H * (N / AT), 256, 0, stream>>>(q, kv, pos, em, aout);
        } else {
            attn2_kernel<<<BATCH * H * (N / AT) * JSPLIT, 256, 0, stream>>>(q, kv, pos, em, opart, mlp);
            attn_combine_kernel<<<ROWS, 256, 0, stream>>>(opart, mlp, aout);
        }
        if (hf32) {
            gemm_kernel<<<dim3(D / BN, ROWS / BM), 256, 0, stream>>>(
                ROWS, D, D, aout, Wo, (size_t)l * D * D, bo, (size_t)l * D, x, nullptr, 1, flag);
            gemm_kernel<<<dim3(4 * D / BN, ROWS / BM), 256, 0, stream>>>(
                ROWS, 4 * D, D, x, W1, (size_t)l * D * 4 * D, b1, (size_t)l * 4 * D, h1, nullptr, 2, flag);
            gemm_kernel<<<dim3(D / BN, ROWS / BM), 256, 0, stream>>>(
                ROWS, D, 4 * D, h1, W2, (size_t)l * 4 * D * D, b2v, (size_t)l * D, x, nullptr, 1, flag);
        } else {
            mgemm_kernel<<<dim3(ROWS / 128, D / 128), 256, 0, stream>>>(
                ROWS, D, D, aout, Wo, (size_t)l * D * D, bo, (size_t)l * D, x, nullptr, 1, flag);
            mgemm_kernel<<<dim3(ROWS / 128, 4 * D / 128), 256, 0, stream>>>(
                ROWS, 4 * D, D, x, W1, (size_t)l * D * 4 * D, b1, (size_t)l * 4 * D, h1, nullptr, 2, flag);
            mgemm_kernel<<<dim3(ROWS / 128, D / 128), 256, 0, stream>>>(
                ROWS, D, 4 * D, h1, W2, (size_t)l * 4 * D * D, b2v, (size_t)l * D, x, nullptr, 1, flag);
        }
    }

    ln_kernel<<<ROWS, 256, 0, stream>>>(x, ln_g, ln_b, y, flag);
    if (hf32) {
        gemm_kernel<<<dim3(V / BN, ROWS / BM), 256, 0, stream>>>(
            ROWS, V, D, y, Whead, 0, nullptr, 0, nullptr, d_out, 0, flag);
    } else {
        mgemm_kernel<<<dim3(ROWS / 128, V / 128), 256, 0, stream>>>(
            ROWS, V, D, y, Whead, 0, nullptr, 0, nullptr, d_out, 0, flag);
    }
    write_aux_kernel<<<1, 64, 0, stream>>>(aux, d_out, flag);
}

// Round 12
// 3477.588 us; speedup vs baseline: 1.0747x; 1.0747x over previous
//
#include <hip/hip_runtime.h>
#include <hip/hip_bf16.h>
#include <math.h>

// Problem constants
#define DEPTH 4
#define D 512
#define H 8
#define DH 64
#define N 1024
#define M 1024
#define V 32000
#define BATCH 2
#define CTXLEN (M + N)         // 2048
#define ROWS (BATCH * N)       // 2048
#define CROWS (BATCH * CTXLEN) // 4096

typedef __hip_bfloat16 bf16;

static __device__ __forceinline__ float b2f(bf16 v) { return __bfloat162float(v); }

// dtype-agnostic load/store: f==1 -> fp32, f==0 -> bf16
static __device__ __forceinline__ float ldf(const void* p, size_t i, int f) {
    return f ? ((const float*)p)[i] : b2f(((const bf16*)p)[i]);
}
static __device__ __forceinline__ void stf(void* p, size_t i, int f, float v) {
    if (f) ((float*)p)[i] = v;
    else   ((bf16*)p)[i] = __float2bfloat16(v);
}
static __device__ __forceinline__ unsigned short f2bits(float v) {
    union { bf16 b; unsigned short u; } cv;
    cv.b = __float2bfloat16(v);
    return cv.u;
}
static __device__ __forceinline__ unsigned short ldbits(const void* p, size_t i, int f) {
    if (f) return f2bits(((const float*)p)[i]);
    return ((const unsigned short*)p)[i];
}
static __device__ __forceinline__ float us2f(unsigned short u) {
    union { float f; unsigned int i; } c;
    c.i = ((unsigned int)u) << 16;
    return c.f;
}
static __device__ __forceinline__ float4 us4f(ushort4 u) {
    float4 r;
    r.x = us2f(u.x); r.y = us2f(u.y); r.z = us2f(u.z); r.w = us2f(u.w);
    return r;
}

// ---------------- dtype detection (device-side, used for data reads) ----------------
__global__ void detect_kernel(const void* __restrict__ p, int* __restrict__ flag,
                              float* __restrict__ aux) {
    __shared__ int cnt;
    if (threadIdx.x == 0) cnt = 0;
    __syncthreads();
    int bad = 0;
    for (int i = threadIdx.x; i < 1024; i += 256) {
        float v = b2f(((const bf16*)p)[i]);
        if (!(fabsf(v) < 16.0f)) bad++;   // NaN also counts as bad
    }
    if (bad) atomicAdd(&cnt, bad);
    __syncthreads();
    if (threadIdx.x == 0) *flag = (cnt >= 8) ? 1 : 0;
    if (threadIdx.x < BATCH) aux[threadIdx.x] = 0.0f;
}

// ---------------- embedding ----------------
__global__ __launch_bounds__(256) void embed_kernel(const int* __restrict__ tokens,
                                                    const void* __restrict__ emb,
                                                    float* __restrict__ x,
                                                    const int* __restrict__ dflag) {
    int f = *dflag;
    int row = blockIdx.x;                 // b*N + i
    int tok = tokens[row];
    float* xr = x + (size_t)row * D;
    for (int d = threadIdx.x; d < D; d += 256)
        xr[d] = ldf(emb, (size_t)tok * D + d, f);
}

// ---------------- sinusoidal embedding table ----------------
__global__ __launch_bounds__(256) void pe_kernel(float* __restrict__ pe) {
    int r = blockIdx.x;
    int k = threadIdx.x;                  // 0..255 (freq index)
    float t = (float)(N - 1 - r);
    float inv = expf(-(float)k * (9.210340371976184f / 256.0f)); // 10000^{-k/256}
    float s = t * inv;
    pe[(size_t)r * D + k]       = sinf(s);
    pe[(size_t)r * D + 256 + k] = cosf(s);
}

// ---------------- expire span gating (per layer) ----------------
__global__ __launch_bounds__(256) void expire_kernel(const void* __restrict__ mems,
                                                     size_t memOff,
                                                     const int* __restrict__ times_l,
                                                     const void* __restrict__ Wexp,
                                                     size_t wOff,
                                                     const void* __restrict__ bexp,
                                                     size_t bOff,
                                                     float* __restrict__ em,
                                                     float* __restrict__ aux,
                                                     const int* __restrict__ dflag) {
    int f = *dflag;
    int wave = (blockIdx.x * 256 + threadIdx.x) >> 6;  // global j over B*M
    int lane = threadIdx.x & 63;
    int b = wave / M, j = wave % M;
    size_t rbase = memOff + ((size_t)b * M + j) * D;
    float s = 0.0f;
    for (int d = lane; d < D; d += 64)
        s += ldf(mems, rbase + d, f) * ldf(Wexp, wOff + d, f);
    #pragma unroll
    for (int off = 32; off > 0; off >>= 1) s += __shfl_xor(s, off, 64);
    if (lane == 0) {
        s += ldf(bexp, bOff, f);
        float e = 1024.0f / (1.0f + expf(-s));      // sigmoid * MAXMEM
        float t = (float)times_l[b * M + j];
        float emv = (e - t) * (1.0f / 128.0f) + 1.0f;
        emv = fminf(fmaxf(emv, 0.0f), 1.0f);
        em[b * M + j] = emv;
        if (emv > 0.0f && emv < 1.0f)
            atomicAdd(&aux[b], e * (1.0f / (128.0f * 1024.0f)));
    }
}

// ---------------- ctx = concat(mem, x) fp32 ----------------
__global__ __launch_bounds__(256) void ctx_kernel(const void* __restrict__ mems,
                                                  size_t memOff,
                                                  const float* __restrict__ x,
                                                  float* __restrict__ ctx,
                                                  const int* __restrict__ dflag) {
    int f = *dflag;
    size_t idx = (size_t)blockIdx.x * 256 + threadIdx.x;  // over B*CTXLEN*D
    int d = idx & (D - 1);
    size_t rowg = idx >> 9;      // /D
    int p = rowg & (CTXLEN - 1);
    int b = rowg >> 11;          // /CTXLEN
    if (p < M) ctx[idx] = ldf(mems, memOff + ((size_t)b * M + p) * D + d, f);
    else       ctx[idx] = x[((size_t)b * N + (p - M)) * D + d];
}

// ---------------- generic tiled VALU GEMM (fp32-exact fallback + tiny pos GEMM) ----------------
#define BM 64
#define BN 64
#define BK 16
__global__ __launch_bounds__(256) void gemm_kernel(int Mm, int Nn, int Kk,
                                                   const float* __restrict__ A,
                                                   const void* __restrict__ Bw, size_t bwOff,
                                                   const void* __restrict__ bias, size_t biasOff,
                                                   float* __restrict__ C,
                                                   void* __restrict__ Cb,
                                                   int epi,
                                                   const int* __restrict__ dflag) {
    int f = *dflag;
    __shared__ __align__(16) float As[BK][BM + 4];
    __shared__ __align__(16) float Bs[BK][BN + 4];
    int tid = threadIdx.x;
    int bm = blockIdx.y * BM;
    int bn = blockIdx.x * BN;
    int tx = tid & 15, ty = tid >> 4;
    int ka = tid & 15, ma = tid >> 4;   // A loads
    int nb = tid & 63, kb = tid >> 6;   // B loads
    float acc[4][4] = {};
    for (int k0 = 0; k0 < Kk; k0 += BK) {
        #pragma unroll
        for (int p = 0; p < 4; ++p)
            As[ka][ma + 16 * p] = A[(size_t)(bm + ma + 16 * p) * Kk + k0 + ka];
        #pragma unroll
        for (int p = 0; p < 4; ++p)
            Bs[kb + 4 * p][nb] = ldf(Bw, bwOff + (size_t)(k0 + kb + 4 * p) * Nn + bn + nb, f);
        __syncthreads();
        #pragma unroll
        for (int k = 0; k < BK; ++k) {
            float4 a4 = *(const float4*)&As[k][ty * 4];
            float4 b4 = *(const float4*)&Bs[k][tx * 4];
            float a[4] = {a4.x, a4.y, a4.z, a4.w};
            float b[4] = {b4.x, b4.y, b4.z, b4.w};
            #pragma unroll
            for (int i = 0; i < 4; ++i)
                #pragma unroll
                for (int j = 0; j < 4; ++j)
                    acc[i][j] += a[i] * b[j];
        }
        __syncthreads();
    }
    #pragma unroll
    for (int i = 0; i < 4; ++i) {
        int row = bm + ty * 4 + i;
        #pragma unroll
        for (int j = 0; j < 4; ++j) {
            int col = bn + tx * 4 + j;
            float v = acc[i][j];
            if (bias) v += ldf(bias, biasOff + col, f);
            size_t idx = (size_t)row * Nn + col;
            if (epi == 2) v = 0.5f * v * (1.0f + erff(v * 0.70710678118654752f));
            if (Cb) { stf(Cb, idx, f, v); }
            else {
                if (epi == 1) v += C[idx];
                C[idx] = v;
            }
        }
    }
}

// ---------------- MFMA bf16 GEMM: C[M,N] = A[M,K](f32 ws) * B[K,N](weights) + bias ----------------
typedef __attribute__((ext_vector_type(8))) short bfrag;   // 8 bf16 (4 VGPRs)
typedef __attribute__((ext_vector_type(4))) float ffrag;   // 4 f32 accum

__global__ __launch_bounds__(256) void mgemm_kernel(int Mm, int Nn, int Kk,
                                                    const float* __restrict__ A,
                                                    const void* __restrict__ Bw, size_t bwOff,
                                                    const void* __restrict__ bias, size_t biasOff,
                                                    float* __restrict__ C,
                                                    void* __restrict__ Cb,
                                                    int epi,
                                                    const int* __restrict__ dflag) {
    int f = *dflag;
    __shared__ __align__(16) unsigned short As[128][48];   // 12 KB
    __shared__ __align__(16) unsigned short Bs[4096];      // 8 KB, frag-ordered [nb][g][c][e]

    int tid = threadIdx.x;
    int bm = blockIdx.x * 128;
    int bn = blockIdx.y * 128;

    // A staging: thread -> (row, 16-wide k half)
    int arow = tid >> 1;
    int akq  = (tid & 1) * 16;
    // wave/lane decomposition
    int wv = tid >> 6;
    int wr = (wv >> 1) * 64;
    int wc = (wv & 1) * 64;
    int lane = tid & 63;
    int lr = lane & 15;
    int lg = lane >> 4;
    int nbBase = wc >> 4;

    ffrag acc[4][4] = {};

    for (int k0 = 0; k0 < Kk; k0 += 32) {
        // ---- stage A (fp32 -> bf16) ----
        const float* Ar = A + (size_t)(bm + arow) * Kk + k0 + akq;
        #pragma unroll
        for (int c = 0; c < 4; ++c) {
            float4 v = *(const float4*)(Ar + 4 * c);
            ushort4 h;
            h.x = f2bits(v.x); h.y = f2bits(v.y); h.z = f2bits(v.z); h.w = f2bits(v.w);
            *(ushort4*)&As[arow][akq + 4 * c] = h;
        }
        // ---- stage B: vectorized along n, scatter to frag order ----
        #pragma unroll
        for (int cc2 = 0; cc2 < 2; ++cc2) {
            int chunk = tid * 2 + cc2;
            int kr = chunk >> 4;              // 0..31
            int cg = chunk & 15;              // col-group of 8
            int colb = cg * 8;
            unsigned short val[8];
            if (f) {
                const float* src = (const float*)Bw + bwOff + (size_t)(k0 + kr) * Nn + bn + colb;
                float4 v0 = *(const float4*)src;
                float4 v1 = *(const float4*)(src + 4);
                val[0] = f2bits(v0.x); val[1] = f2bits(v0.y);
                val[2] = f2bits(v0.z); val[3] = f2bits(v0.w);
                val[4] = f2bits(v1.x); val[5] = f2bits(v1.y);
                val[6] = f2bits(v1.z); val[7] = f2bits(v1.w);
            } else {
                const unsigned short* src = (const unsigned short*)Bw + bwOff
                                          + (size_t)(k0 + kr) * Nn + bn + colb;
                uint4 u = *(const uint4*)src;
                *(uint4*)val = u;
            }
            int g = kr >> 3, ke = kr & 7;
            int base = (((cg >> 1) * 4 + g) * 16 + 8 * (cg & 1));
            #pragma unroll
            for (int j = 0; j < 8; ++j)
                Bs[(base + j) * 8 + ke] = val[j];
        }
        __syncthreads();
        // ---- fragments + MFMA ----
        bfrag af[4], bfv[4];
        #pragma unroll
        for (int m = 0; m < 4; ++m)
            af[m] = *(const bfrag*)&As[wr + m * 16 + lr][lg * 8];
        #pragma unroll
        for (int n = 0; n < 4; ++n)
            bfv[n] = *(const bfrag*)&Bs[(((nbBase + n) * 4 + lg) * 16 + lr) * 8];
        #pragma unroll
        for (int m = 0; m < 4; ++m)
            #pragma unroll
            for (int n = 0; n < 4; ++n)
                acc[m][n] = __builtin_amdgcn_mfma_f32_16x16x32_bf16(af[m], bfv[n], acc[m][n], 0, 0, 0);
        __syncthreads();
    }
    // ---- epilogue: D layout col=lane&15, row=(lane>>4)*4+j ----
    #pragma unroll
    for (int m = 0; m < 4; ++m) {
        int row0 = bm + wr + m * 16 + lg * 4;
        #pragma unroll
        for (int n = 0; n < 4; ++n) {
            int col = bn + wc + n * 16 + lr;
            float bv = bias ? ldf(bias, biasOff + col, f) : 0.0f;
            #pragma unroll
            for (int j = 0; j < 4; ++j) {
                int row = row0 + j;
                float v = acc[m][n][j] + bv;
                size_t idx = (size_t)row * Nn + col;
                if (epi == 2) v = 0.5f * v * (1.0f + erff(v * 0.70710678118654752f));
                if (Cb) { stf(Cb, idx, f, v); }
                else {
                    if (epi == 1) v += C[idx];
                    C[idx] = v;
                }
            }
        }
    }
}

// ---------------- flash-tiled attention (fp32-exact path, AT=32) ----------------
#define AT 32
#define JT 64
__global__ __launch_bounds__(256) void attn_kernel(const float* __restrict__ q,
                                                   const float* __restrict__ kv,
                                                   const float* __restrict__ pos,
                                                   const float* __restrict__ em,
                                                   float* __restrict__ outp) {
    __shared__ __align__(16) float Qs[AT][68];
    __shared__ __align__(16) float KVs[JT][68];
    __shared__ __align__(16) float Ss[AT][65];
    __shared__ __align__(16) float Ps[95][68];
    __shared__ float gates[M];
    __shared__ float mrow[AT], lrow[AT], arow[AT];

    int t = threadIdx.x;
    int bid = blockIdx.x;
    int raw = bid & 31;
    int it = (raw & 1) ? (31 - (raw >> 1)) : (raw >> 1);
    int h = (bid >> 5) & 7;
    int b = bid >> 8;
    int i0 = it * AT;

    for (int idx = t; idx < AT * 64; idx += 256) {
        int il = idx >> 6, d = idx & 63;
        Qs[il][d] = q[((size_t)(b * N + i0 + il)) * D + h * DH + d];
    }
    for (int idx = t; idx < M; idx += 256) gates[idx] = em[b * M + idx];
    if (t < AT) { mrow[t] = -3e38f; lrow[t] = 0.0f; arow[t] = 0.0f; }

    int ti = t >> 4;
    int tj = t & 15;
    float O[2][4] = {};

    int nx = ((i0 + AT - 1) >> 6) + 1;
    int ntiles = M / JT + nx;
    for (int tile = 0; tile < ntiles; ++tile) {
        int t0 = tile * JT;
        int t0x = t0 - M;
        __syncthreads();
        for (int idx = t; idx < JT * 64; idx += 256) {
            int jl = idx >> 6, d = idx & 63;
            KVs[jl][d] = kv[((size_t)(b * CTXLEN + t0 + jl)) * (2 * D) + h * DH + d];
        }
        int r0 = N - 1 - (i0 + AT - 1) + t0x;
        if (t0x >= 0) {
            for (int idx = t; idx < 95 * 64; idx += 256) {
                int w = idx >> 6, d = idx & 63;
                int r = r0 + w; r = r > (N - 1) ? (N - 1) : r;
                Ps[w][d] = pos[(size_t)r * DH + d];
            }
        }
        __syncthreads();
        float s[2][4] = {};
        #pragma unroll
        for (int d4 = 0; d4 < 16; ++d4) {
            float4 qv[2], kv4[4];
            #pragma unroll
            for (int rr = 0; rr < 2; ++rr) qv[rr] = *(const float4*)&Qs[2 * ti + rr][4 * d4];
            #pragma unroll
            for (int cc = 0; cc < 4; ++cc) kv4[cc] = *(const float4*)&KVs[tj + 16 * cc][4 * d4];
            #pragma unroll
            for (int rr = 0; rr < 2; ++rr)
                #pragma unroll
                for (int cc = 0; cc < 4; ++cc)
                    s[rr][cc] += qv[rr].x * kv4[cc].x + qv[rr].y * kv4[cc].y
                               + qv[rr].z * kv4[cc].z + qv[rr].w * kv4[cc].w;
        }
        if (t0x >= 0) {
            #pragma unroll 4
            for (int d4 = 0; d4 < 16; ++d4) {
                float4 qv[2];
                #pragma unroll
                for (int rr = 0; rr < 2; ++rr) qv[rr] = *(const float4*)&Qs[2 * ti + rr][4 * d4];
                #pragma unroll
                for (int rr = 0; rr < 2; ++rr) {
                    int wb = (AT - 1) - (2 * ti + rr);
                    #pragma unroll
                    for (int cc = 0; cc < 4; ++cc) {
                        float4 pv = *(const float4*)&Ps[tj + 16 * cc + wb][4 * d4];
                        s[rr][cc] += qv[rr].x * pv.x + qv[rr].y * pv.y
                                   + qv[rr].z * pv.z + qv[rr].w * pv.w;
                    }
                }
            }
        }
        #pragma unroll
        for (int rr = 0; rr < 2; ++rr) {
            int il = 2 * ti + rr;
            #pragma unroll
            for (int cc = 0; cc < 4; ++cc) {
                int jl = tj + 16 * cc;
                float v = s[rr][cc] * 0.125f;
                if (t0x >= 0 && (t0x + jl) > (i0 + il)) v = -3e38f;
                Ss[il][jl] = v;
            }
        }
        __syncthreads();
        for (int idx = t; idx < JT * 64; idx += 256) {
            int jl = idx >> 6, d = idx & 63;
            KVs[jl][d] = kv[((size_t)(b * CTXLEN + t0 + jl)) * (2 * D) + D + h * DH + d];
        }
        if (t < AT) {
            int il = t;
            float mo = mrow[il];
            float tmax = -3e38f;
            for (int j = 0; j < JT; ++j) tmax = fmaxf(tmax, Ss[il][j]);
            float mn = fmaxf(mo, tmax);
            float alpha = expf(mo - mn);
            float sum = 0.0f;
            for (int j = 0; j < JT; ++j) {
                float e = expf(Ss[il][j] - mn);
                sum += e;
                int jg = t0 + j;
                float g = (jg < M) ? gates[jg] : 1.0f;
                Ss[il][j] = e * g;
            }
            lrow[il] = lrow[il] * alpha + sum;
            mrow[il] = mn;
            arow[il] = alpha;
        }
        __syncthreads();
        float a0 = arow[2 * ti], a1 = arow[2 * ti + 1];
        #pragma unroll
        for (int dd = 0; dd < 4; ++dd) { O[0][dd] *= a0; O[1][dd] *= a1; }
        #pragma unroll
        for (int jb = 0; jb < 16; ++jb) {
            float4 p0 = *(const float4*)&Ss[2 * ti][4 * jb];
            float4 p1 = *(const float4*)&Ss[2 * ti + 1][4 * jb];
            float4 v0 = *(const float4*)&KVs[4 * jb + 0][4 * tj];
            float4 v1 = *(const float4*)&KVs[4 * jb + 1][4 * tj];
            float4 v2 = *(const float4*)&KVs[4 * jb + 2][4 * tj];
            float4 v3 = *(const float4*)&KVs[4 * jb + 3][4 * tj];
            O[0][0] += p0.x * v0.x + p0.y * v1.x + p0.z * v2.x + p0.w * v3.x;
            O[0][1] += p0.x * v0.y + p0.y * v1.y + p0.z * v2.y + p0.w * v3.y;
            O[0][2] += p0.x * v0.z + p0.y * v1.z + p0.z * v2.z + p0.w * v3.z;
            O[0][3] += p0.x * v0.w + p0.y * v1.w + p0.z * v2.w + p0.w * v3.w;
            O[1][0] += p1.x * v0.x + p1.y * v1.x + p1.z * v2.x + p1.w * v3.x;
            O[1][1] += p1.x * v0.y + p1.y * v1.y + p1.z * v2.y + p1.w * v3.y;
            O[1][2] += p1.x * v0.z + p1.y * v1.z + p1.z * v2.z + p1.w * v3.z;
            O[1][3] += p1.x * v0.w + p1.y * v1.w + p1.z * v2.w + p1.w * v3.w;
        }
    }
    #pragma unroll
    for (int rr = 0; rr < 2; ++rr) {
        int il = 2 * ti + rr;
        float inv = 1.0f / lrow[il];
        float4 r4;
        r4.x = O[rr][0] * inv; r4.y = O[rr][1] * inv;
        r4.z = O[rr][2] * inv; r4.w = O[rr][3] * inv;
        *(float4*)&outp[((size_t)(b * N + i0 + il)) * D + h * DH + 4 * tj] = r4;
    }
}

// ---------------- attention v2 (bf16 path): in-wave softmax, 2 barriers/tile, j-split ----------------
// Round-4 harness-passed kernel + T14 async-STAGE split: next tile's K/V global loads
// are issued at the START of the compute phase (registers), written to LDS at the next
// loop top. Barrier structure and numerics unchanged.
#define JSPLIT 2
__global__ __launch_bounds__(256) void attn2_kernel(const float* __restrict__ q,
                                                    const float* __restrict__ kv,
                                                    const float* __restrict__ pos,
                                                    const float* __restrict__ em,
                                                    float* __restrict__ opart,
                                                    float* __restrict__ mlp) {
    __shared__ __align__(16) float          Qs[AT][68];    // 8704 B
    __shared__ __align__(16) unsigned short Kb[JT][72];    // 9216 B
    __shared__ __align__(16) unsigned short Vb[JT][72];    // 9216 B
    __shared__ __align__(16) float          Pw[AT][68];    // 8704 B
    __shared__ __align__(16) unsigned short Psb[95][72];   // 13680 B
    // total 49520 B -> 3 blocks/CU

    int t = threadIdx.x;
    int bid = blockIdx.x;
    int p   = bid & 1;                 // j-split parity
    int raw = (bid >> 1) & 31;
    int it = (raw & 1) ? (31 - (raw >> 1)) : (raw >> 1);
    int h = (bid >> 6) & 7;
    int b = bid >> 9;
    int i0 = it * AT;

    // stage Q (float4)
    for (int idx = t; idx < AT * 16; idx += 256) {
        int il = idx >> 4, d4 = idx & 15;
        *(float4*)&Qs[il][4 * d4] =
            *(const float4*)&q[((size_t)(b * N + i0 + il)) * D + h * DH + 4 * d4];
    }

    int ti = t >> 4;       // 0..15 -> rows 2ti+rr (16 consecutive lanes per row pair)
    int tj = t & 15;       // S col lane / PV d-chunk
    float O[2][4] = {};
    float mo[2] = {-3e38f, -3e38f};
    float lo[2] = {0.0f, 0.0f};

    int nx = ((i0 + AT - 1) >> 6) + 1;
    int ntiles = M / JT + nx;

    // ---- prologue: prefetch first tile's K/V into registers ----
    float4 kpre[4], vpre[4];
    {
        int t0 = p * JT;
        #pragma unroll
        for (int i = 0; i < 4; ++i) {
            int idx = t + i * 256;
            int jl = idx >> 4, d4 = idx & 15;
            const float* base = &kv[(size_t)(b * CTXLEN + t0 + jl) * (2 * D) + h * DH + 4 * d4];
            kpre[i] = *(const float4*)base;
            vpre[i] = *(const float4*)(base + D);
        }
    }

    for (int tile = p; tile < ntiles; tile += JSPLIT) {
        int t0x = tile * JT - M;
        __syncthreads();                 // prev tile's K/V reads complete
        // ---- write prefetched K/V registers to LDS (bf16) ----
        #pragma unroll
        for (int i = 0; i < 4; ++i) {
            int idx = t + i * 256;
            int jl = idx >> 4, d4 = idx & 15;
            ushort4 ku, vu;
            ku.x = f2bits(kpre[i].x); ku.y = f2bits(kpre[i].y);
            ku.z = f2bits(kpre[i].z); ku.w = f2bits(kpre[i].w);
            vu.x = f2bits(vpre[i].x); vu.y = f2bits(vpre[i].y);
            vu.z = f2bits(vpre[i].z); vu.w = f2bits(vpre[i].w);
            *(ushort4*)&Kb[jl][4 * d4] = ku;
            *(ushort4*)&Vb[jl][4 * d4] = vu;
        }
        // ---- stage pos window (bf16, vectorized) for x-tiles ----
        if (t0x >= 0) {
            int r0 = N - 1 - (i0 + AT - 1) + t0x;
            for (int idx = t; idx < 95 * 8; idx += 256) {
                int w = idx >> 3, c = idx & 7;
                int r = r0 + w; r = r > (N - 1) ? (N - 1) : r;
                const float* pp = &pos[(size_t)r * DH + 8 * c];
                float4 a = *(const float4*)pp;
                float4 bb = *(const float4*)(pp + 4);
                ushort4 u0, u1;
                u0.x = f2bits(a.x);  u0.y = f2bits(a.y);  u0.z = f2bits(a.z);  u0.w = f2bits(a.w);
                u1.x = f2bits(bb.x); u1.y = f2bits(bb.y); u1.z = f2bits(bb.z); u1.w = f2bits(bb.w);
                *(ushort4*)&Psb[w][8 * c]     = u0;
                *(ushort4*)&Psb[w][8 * c + 4] = u1;
            }
        }
        __syncthreads();                 // K/V/Ps ready
        // ---- issue NEXT tile's K/V loads (latency hides under compute) ----
        if (tile + JSPLIT < ntiles) {
            int t0n = (tile + JSPLIT) * JT;
            #pragma unroll
            for (int i = 0; i < 4; ++i) {
                int idx = t + i * 256;
                int jl = idx >> 4, d4 = idx & 15;
                const float* base = &kv[(size_t)(b * CTXLEN + t0n + jl) * (2 * D) + h * DH + 4 * d4];
                kpre[i] = *(const float4*)base;
                vpre[i] = *(const float4*)(base + D);
            }
        }
        // ---- S = Q K^T ----
        float s[2][4] = {};
        #pragma unroll
        for (int d4 = 0; d4 < 16; ++d4) {
            float4 q0 = *(const float4*)&Qs[2 * ti][4 * d4];
            float4 q1 = *(const float4*)&Qs[2 * ti + 1][4 * d4];
            #pragma unroll
            for (int cc = 0; cc < 4; ++cc) {
                float4 kf = us4f(*(const ushort4*)&Kb[tj + 16 * cc][4 * d4]);
                s[0][cc] += q0.x * kf.x + q0.y * kf.y + q0.z * kf.z + q0.w * kf.w;
                s[1][cc] += q1.x * kf.x + q1.y * kf.y + q1.z * kf.z + q1.w * kf.w;
            }
        }
        // ---- + pos skew (x-tiles) ----
        if (t0x >= 0) {
            int wb0 = (AT - 1) - 2 * ti;
            int wb1 = wb0 - 1;
            #pragma unroll 4
            for (int d4 = 0; d4 < 16; ++d4) {
                float4 q0 = *(const float4*)&Qs[2 * ti][4 * d4];
                float4 q1 = *(const float4*)&Qs[2 * ti + 1][4 * d4];
                #pragma unroll
                for (int cc = 0; cc < 4; ++cc) {
                    float4 p0 = us4f(*(const ushort4*)&Psb[tj + 16 * cc + wb0][4 * d4]);
                    float4 p1 = us4f(*(const ushort4*)&Psb[tj + 16 * cc + wb1][4 * d4]);
                    s[0][cc] += q0.x * p0.x + q0.y * p0.y + q0.z * p0.z + q0.w * p0.w;
                    s[1][cc] += q1.x * p1.x + q1.y * p1.y + q1.z * p1.z + q1.w * p1.w;
                }
            }
        }
        // ---- scale + causal mask ----
        #pragma unroll
        for (int rr = 0; rr < 2; ++rr) {
            int il = 2 * ti + rr;
            #pragma unroll
            for (int cc = 0; cc < 4; ++cc) {
                float v = s[rr][cc] * 0.125f;
                int jl = tj + 16 * cc;
                if (t0x >= 0 && (t0x + jl) > (i0 + il)) v = -3e38f;
                s[rr][cc] = v;
            }
        }
        // ---- gates (global, L1-broadcast) ----
        float g4[4];
        #pragma unroll
        for (int cc = 0; cc < 4; ++cc) {
            int jg = tile * JT + tj + 16 * cc;
            g4[cc] = (jg < M) ? em[b * M + jg] : 1.0f;
        }
        // ---- in-wave online softmax (width-16 shuffles; rows live in 16-lane groups) ----
        #pragma unroll
        for (int rr = 0; rr < 2; ++rr) {
            float tmax = fmaxf(fmaxf(s[rr][0], s[rr][1]), fmaxf(s[rr][2], s[rr][3]));
            tmax = fmaxf(tmax, __shfl_xor(tmax, 8, 16));
            tmax = fmaxf(tmax, __shfl_xor(tmax, 4, 16));
            tmax = fmaxf(tmax, __shfl_xor(tmax, 2, 16));
            tmax = fmaxf(tmax, __shfl_xor(tmax, 1, 16));
            float mn = fmaxf(mo[rr], tmax);
            float al = __expf(mo[rr] - mn);
            mo[rr] = mn;
            float sum = 0.0f;
            float pv4[4];
            #pragma unroll
            for (int cc = 0; cc < 4; ++cc) {
                float e = __expf(s[rr][cc] - mn);
                sum += e;
                pv4[cc] = e * g4[cc];
            }
            sum += __shfl_xor(sum, 8, 16);
            sum += __shfl_xor(sum, 4, 16);
            sum += __shfl_xor(sum, 2, 16);
            sum += __shfl_xor(sum, 1, 16);
            lo[rr] = lo[rr] * al + sum;
            #pragma unroll
            for (int dd = 0; dd < 4; ++dd) O[rr][dd] *= al;
            int il = 2 * ti + rr;
            #pragma unroll
            for (int cc = 0; cc < 4; ++cc) Pw[il][tj + 16 * cc] = pv4[cc];
        }
        // ---- PV (P rows written by this wave; wave64 lockstep -> no barrier) ----
        #pragma unroll
        for (int jb = 0; jb < 16; ++jb) {
            float4 p0 = *(const float4*)&Pw[2 * ti][4 * jb];
            float4 p1 = *(const float4*)&Pw[2 * ti + 1][4 * jb];
            float4 v0 = us4f(*(const ushort4*)&Vb[4 * jb + 0][4 * tj]);
            float4 v1 = us4f(*(const ushort4*)&Vb[4 * jb + 1][4 * tj]);
            float4 v2 = us4f(*(const ushort4*)&Vb[4 * jb + 2][4 * tj]);
            float4 v3 = us4f(*(const ushort4*)&Vb[4 * jb + 3][4 * tj]);
            O[0][0] += p0.x * v0.x + p0.y * v1.x + p0.z * v2.x + p0.w * v3.x;
            O[0][1] += p0.x * v0.y + p0.y * v1.y + p0.z * v2.y + p0.w * v3.y;
            O[0][2] += p0.x * v0.z + p0.y * v1.z + p0.z * v2.z + p0.w * v3.z;
            O[0][3] += p0.x * v0.w + p0.y * v1.w + p0.z * v2.w + p0.w * v3.w;
            O[1][0] += p1.x * v0.x + p1.y * v1.x + p1.z * v2.x + p1.w * v3.x;
            O[1][1] += p1.x * v0.y + p1.y * v1.y + p1.z * v2.y + p1.w * v3.y;
            O[1][2] += p1.x * v0.z + p1.y * v1.z + p1.z * v2.z + p1.w * v3.z;
            O[1][3] += p1.x * v0.w + p1.y * v1.w + p1.z * v2.w + p1.w * v3.w;
        }
    }
    // ---- write unnormalized partials + (m,l) ----
    size_t ob = ((size_t)((p * BATCH + b) * H + h) * N + i0) * DH;
    #pragma unroll
    for (int rr = 0; rr < 2; ++rr) {
        int il = 2 * ti + rr;
        float4 r4;
        r4.x = O[rr][0]; r4.y = O[rr][1]; r4.z = O[rr][2]; r4.w = O[rr][3];
        *(float4*)&opart[ob + (size_t)il * DH + 4 * tj] = r4;
        if (tj == 0) {
            size_t mlIdx = (((size_t)(p * BATCH + b) * H + h) * N + i0 + il) * 2;
            mlp[mlIdx]     = mo[rr];
            mlp[mlIdx + 1] = lo[rr];
        }
    }
}

// ---------------- combine j-split partials ----------------
__global__ __launch_bounds__(256) void attn_combine_kernel(const float* __restrict__ opart,
                                                           const float* __restrict__ mlp,
                                                           float* __restrict__ aout) {
    int row = blockIdx.x;            // b*N + i
    int b = row >> 10;
    int i = row & (N - 1);
    for (int d = threadIdx.x; d < D; d += 256) {
        int h = d >> 6, dd = d & 63;
        size_t s0 = ((size_t)(b * H + h) * N + i);
        size_t s1 = ((size_t)((BATCH + b) * H + h) * N + i);
        float m0 = mlp[s0 * 2], l0 = mlp[s0 * 2 + 1];
        float m1 = mlp[s1 * 2], l1 = mlp[s1 * 2 + 1];
        float m = fmaxf(m0, m1);
        float w0 = __expf(m0 - m), w1 = __expf(m1 - m);
        float denom = l0 * w0 + l1 * w1;
        aout[(size_t)row * D + d] = (opart[s0 * DH + dd] * w0 + opart[s1 * DH + dd] * w1) / denom;
    }
}

// ---------------- final layernorm ----------------
__global__ __launch_bounds__(256) void ln_kernel(const float* __restrict__ x,
                                                 const void* __restrict__ g,
                                                 const void* __restrict__ bta,
                                                 float* __restrict__ y,
                                                 const int* __restrict__ dflag) {
    int f = *dflag;
    int row = blockIdx.x;
    const float* xr = x + (size_t)row * D;
    __shared__ float red[4];
    int lane = threadIdx.x & 63, wv = threadIdx.x >> 6;
    float s = 0.0f;
    for (int d = threadIdx.x; d < D; d += 256) s += xr[d];
    #pragma unroll
    for (int off = 32; off > 0; off >>= 1) s += __shfl_xor(s, off, 64);
    if (lane == 0) red[wv] = s;
    __syncthreads();
    float mu = (red[0] + red[1] + red[2] + red[3]) * (1.0f / D);
    __syncthreads();
    float v = 0.0f;
    for (int d = threadIdx.x; d < D; d += 256) { float tt = xr[d] - mu; v += tt * tt; }
    #pragma unroll
    for (int off = 32; off > 0; off >>= 1) v += __shfl_xor(v, off, 64);
    if (lane == 0) red[wv] = v;
    __syncthreads();
    float var = (red[0] + red[1] + red[2] + red[3]) * (1.0f / D);
    float rstd = 1.0f / sqrtf(var + 1e-5f);
    for (int d = threadIdx.x; d < D; d += 256)
        y[(size_t)row * D + d] = (xr[d] - mu) * rstd * ldf(g, d, f) + ldf(bta, d, f);
}

// ---------------- aux write ----------------
__global__ void write_aux_kernel(const float* __restrict__ aux, void* __restrict__ out,
                                 const int* __restrict__ dflag) {
    int f = *dflag;
    if (threadIdx.x < BATCH)
        stf(out, (size_t)ROWS * V + threadIdx.x, f, aux[threadIdx.x]);
}

extern "C" void kernel_launch(void* const* d_in, const int* in_sizes, int n_in,
                              void* d_out, int out_size, void* d_ws, size_t ws_size,
                              hipStream_t stream) {
    (void)n_in; (void)out_size; (void)ws_size;
    const int*  tokens  = (const int*)d_in[0];
    const void* mems    = d_in[1];
    const int*  times   = (const int*)d_in[2];
    const void* tok_emb = d_in[3];
    const void* Wq   = d_in[4];
    const void* bq   = d_in[5];
    const void* Wkv  = d_in[6];
    const void* bkv  = d_in[7];
    const void* Wo   = d_in[8];
    const void* bo   = d_in[9];
    const void* Wpos = d_in[10];
    const void* bpos = d_in[11];
    const void* Wexp = d_in[12];
    const void* bexp = d_in[13];
    const void* W1   = d_in[14];
    const void* b1   = d_in[15];
    const void* W2   = d_in[16];
    const void* b2v  = d_in[17];
    const void* ln_g = d_in[18];
    const void* ln_b = d_in[19];
    const void* Whead= d_in[20];

    float* ws  = (float*)d_ws;
    float* x    = ws;                            // ROWS*D
    float* pe   = x    + (size_t)ROWS * D;       // N*D
    float* ctx  = pe   + (size_t)N * D;          // CROWS*D   (y, opart alias)
    float* kv   = ctx  + (size_t)CROWS * D;      // CROWS*2D  (h1 aliases)
    float* q    = kv   + (size_t)CROWS * 2 * D;  // ROWS*D
    float* pos  = q    + (size_t)ROWS * D;       // N*DH
    float* em   = pos  + (size_t)N * DH;         // B*M
    float* aout = em   + (size_t)BATCH * M;      // ROWS*D
    float* aux  = aout + (size_t)ROWS * D;       // 2 floats + flag
    int*   flag = (int*)(aux + 2);
    float* mlp  = aux + 16;                      // JSPLIT*B*H*N*2 = 65,536 floats
    float* h1   = kv;   // alias
    float* y    = ctx;  // alias
    float* opart = ctx; // alias: CROWS*D == JSPLIT*B*H*N*DH floats; ctx dead during attn

    // Host-side dtype guess from staged byte size of tok_emb (V*D elems).
    int hf32 = (in_sizes && in_sizes[3] >= (int)(V * (size_t)D * 3)) ? 1 : 0;

    detect_kernel<<<1, 256, 0, stream>>>(tok_emb, flag, aux);
    embed_kernel<<<ROWS, 256, 0, stream>>>(tokens, tok_emb, x, flag);
    pe_kernel<<<N, 256, 0, stream>>>(pe);

    for (int l = 0; l < DEPTH; ++l) {
        expire_kernel<<<(BATCH * M) / 4, 256, 0, stream>>>(
            mems, (size_t)l * BATCH * M * D, times + (size_t)l * BATCH * M,
            Wexp, (size_t)l * D, bexp, (size_t)l, em, aux, flag);
        ctx_kernel<<<(BATCH * CTXLEN * D) / 256, 256, 0, stream>>>(
            mems, (size_t)l * BATCH * M * D, x, ctx, flag);
        if (hf32) {
            gemm_kernel<<<dim3(D / BN, ROWS / BM), 256, 0, stream>>>(
                ROWS, D, D, x, Wq, (size_t)l * D * D, bq, (size_t)l * D, q, nullptr, 0, flag);
            gemm_kernel<<<dim3(2 * D / BN, CROWS / BM), 256, 0, stream>>>(
                CROWS, 2 * D, D, ctx, Wkv, (size_t)l * D * 2 * D, bkv, (size_t)l * 2 * D, kv, nullptr, 0, flag);
        } else {
            mgemm_kernel<<<dim3(ROWS / 128, D / 128), 256, 0, stream>>>(
                ROWS, D, D, x, Wq, (size_t)l * D * D, bq, (size_t)l * D, q, nullptr, 0, flag);
            mgemm_kernel<<<dim3(CROWS / 128, 2 * D / 128), 256, 0, stream>>>(
                CROWS, 2 * D, D, ctx, Wkv, (size_t)l * D * 2 * D, bkv, (size_t)l * 2 * D, kv, nullptr, 0, flag);
        }
        gemm_kernel<<<dim3(DH / BN, N / BM), 256, 0, stream>>>(
            N, DH, D, pe, Wpos, (size_t)l * D * DH, bpos, (size_t)l * DH, pos, nullptr, 0, flag);
        if (hf32) {
            attn_kernel<<<BATCH * H * (N / AT), 256, 0, stream>>>(q, kv, pos, em, aout);
        } else {
            attn2_kernel<<<BATCH * H * (N / AT) * JSPLIT, 256, 0, stream>>>(q, kv, pos, em, opart, mlp);
            attn_combine_kernel<<<ROWS, 256, 0, stream>>>(opart, mlp, aout);
        }
        if (hf32) {
            gemm_kernel<<<dim3(D / BN, ROWS / BM), 256, 0, stream>>>(
                ROWS, D, D, aout, Wo, (size_t)l * D * D, bo, (size_t)l * D, x, nullptr, 1, flag);
            gemm_kernel<<<dim3(4 * D / BN, ROWS / BM), 256, 0, stream>>>(
                ROWS, 4 * D, D, x, W1, (size_t)l * D * 4 * D, b1, (size_t)l * 4 * D, h1, nullptr, 2, flag);
            gemm_kernel<<<dim3(D / BN, ROWS / BM), 256, 0, stream>>>(
                ROWS, D, 4 * D, h1, W2, (size_t)l * 4 * D * D, b2v, (size_t)l * D, x, nullptr, 1, flag);
        } else {
            mgemm_kernel<<<dim3(ROWS / 128, D / 128), 256, 0, stream>>>(
                ROWS, D, D, aout, Wo, (size_t)l * D * D, bo, (size_t)l * D, x, nullptr, 1, flag);
            mgemm_kernel<<<dim3(ROWS / 128, 4 * D / 128), 256, 0, stream>>>(
                ROWS, 4 * D, D, x, W1, (size_t)l * D * 4 * D, b1, (size_t)l * 4 * D, h1, nullptr, 2, flag);
            mgemm_kernel<<<dim3(ROWS / 128, D / 128), 256, 0, stream>>>(
                ROWS, D, 4 * D, h1, W2, (size_t)l * 4 * D * D, b2v, (size_t)l * D, x, nullptr, 1, flag);
        }
    }

    ln_kernel<<<ROWS, 256, 0, stream>>>(x, ln_g, ln_b, y, flag);
    if (hf32) {
        gemm_kernel<<<dim3(V / BN, ROWS / BM), 256, 0, stream>>>(
            ROWS, V, D, y, Whead, 0, nullptr, 0, nullptr, d_out, 0, flag);
    } else {
        mgemm_kernel<<<dim3(ROWS / 128, V / 128), 256, 0, stream>>>(
            ROWS, V, D, y, Whead, 0, nullptr, 0, nullptr, d_out, 0, flag);
    }
    write_aux_kernel<<<1, 64, 0, stream>>>(aux, d_out, flag);
}

// Round 13
// 3398.241 us; speedup vs baseline: 1.0998x; 1.0233x over previous
//
#include <hip/hip_runtime.h>
#include <hip/hip_bf16.h>
#include <math.h>

// Problem constants
#define DEPTH 4
#define D 512
#define H 8
#define DH 64
#define N 1024
#define M 1024
#define V 32000
#define BATCH 2
#define CTXLEN (M + N)         // 2048
#define ROWS (BATCH * N)       // 2048
#define CROWS (BATCH * CTXLEN) // 4096

typedef __hip_bfloat16 bf16;

static __device__ __forceinline__ float b2f(bf16 v) { return __bfloat162float(v); }

// dtype-agnostic load/store: f==1 -> fp32, f==0 -> bf16
static __device__ __forceinline__ float ldf(const void* p, size_t i, int f) {
    return f ? ((const float*)p)[i] : b2f(((const bf16*)p)[i]);
}
static __device__ __forceinline__ void stf(void* p, size_t i, int f, float v) {
    if (f) ((float*)p)[i] = v;
    else   ((bf16*)p)[i] = __float2bfloat16(v);
}
static __device__ __forceinline__ unsigned short f2bits(float v) {
    union { bf16 b; unsigned short u; } cv;
    cv.b = __float2bfloat16(v);
    return cv.u;
}
static __device__ __forceinline__ unsigned short ldbits(const void* p, size_t i, int f) {
    if (f) return f2bits(((const float*)p)[i]);
    return ((const unsigned short*)p)[i];
}
static __device__ __forceinline__ float us2f(unsigned short u) {
    union { float f; unsigned int i; } c;
    c.i = ((unsigned int)u) << 16;
    return c.f;
}
static __device__ __forceinline__ float4 us4f(ushort4 u) {
    float4 r;
    r.x = us2f(u.x); r.y = us2f(u.y); r.z = us2f(u.z); r.w = us2f(u.w);
    return r;
}

// ---------------- dtype detection (device-side, used for data reads) ----------------
__global__ void detect_kernel(const void* __restrict__ p, int* __restrict__ flag,
                              float* __restrict__ aux) {
    __shared__ int cnt;
    if (threadIdx.x == 0) cnt = 0;
    __syncthreads();
    int bad = 0;
    for (int i = threadIdx.x; i < 1024; i += 256) {
        float v = b2f(((const bf16*)p)[i]);
        if (!(fabsf(v) < 16.0f)) bad++;   // NaN also counts as bad
    }
    if (bad) atomicAdd(&cnt, bad);
    __syncthreads();
    if (threadIdx.x == 0) *flag = (cnt >= 8) ? 1 : 0;
    if (threadIdx.x < BATCH) aux[threadIdx.x] = 0.0f;
}

// ---------------- embedding ----------------
__global__ __launch_bounds__(256) void embed_kernel(const int* __restrict__ tokens,
                                                    const void* __restrict__ emb,
                                                    float* __restrict__ x,
                                                    const int* __restrict__ dflag) {
    int f = *dflag;
    int row = blockIdx.x;                 // b*N + i
    int tok = tokens[row];
    float* xr = x + (size_t)row * D;
    for (int d = threadIdx.x; d < D; d += 256)
        xr[d] = ldf(emb, (size_t)tok * D + d, f);
}

// ---------------- sinusoidal embedding table ----------------
__global__ __launch_bounds__(256) void pe_kernel(float* __restrict__ pe) {
    int r = blockIdx.x;
    int k = threadIdx.x;                  // 0..255 (freq index)
    float t = (float)(N - 1 - r);
    float inv = expf(-(float)k * (9.210340371976184f / 256.0f)); // 10000^{-k/256}
    float s = t * inv;
    pe[(size_t)r * D + k]       = sinf(s);
    pe[(size_t)r * D + 256 + k] = cosf(s);
}

// ---------------- expire span gating (per layer) ----------------
__global__ __launch_bounds__(256) void expire_kernel(const void* __restrict__ mems,
                                                     size_t memOff,
                                                     const int* __restrict__ times_l,
                                                     const void* __restrict__ Wexp,
                                                     size_t wOff,
                                                     const void* __restrict__ bexp,
                                                     size_t bOff,
                                                     float* __restrict__ em,
                                                     float* __restrict__ aux,
                                                     const int* __restrict__ dflag) {
    int f = *dflag;
    int wave = (blockIdx.x * 256 + threadIdx.x) >> 6;  // global j over B*M
    int lane = threadIdx.x & 63;
    int b = wave / M, j = wave % M;
    size_t rbase = memOff + ((size_t)b * M + j) * D;
    float s = 0.0f;
    for (int d = lane; d < D; d += 64)
        s += ldf(mems, rbase + d, f) * ldf(Wexp, wOff + d, f);
    #pragma unroll
    for (int off = 32; off > 0; off >>= 1) s += __shfl_xor(s, off, 64);
    if (lane == 0) {
        s += ldf(bexp, bOff, f);
        float e = 1024.0f / (1.0f + expf(-s));      // sigmoid * MAXMEM
        float t = (float)times_l[b * M + j];
        float emv = (e - t) * (1.0f / 128.0f) + 1.0f;
        emv = fminf(fmaxf(emv, 0.0f), 1.0f);
        em[b * M + j] = emv;
        if (emv > 0.0f && emv < 1.0f)
            atomicAdd(&aux[b], e * (1.0f / (128.0f * 1024.0f)));
    }
}

// ---------------- ctx = concat(mem, x) fp32 ----------------
__global__ __launch_bounds__(256) void ctx_kernel(const void* __restrict__ mems,
                                                  size_t memOff,
                                                  const float* __restrict__ x,
                                                  float* __restrict__ ctx,
                                                  const int* __restrict__ dflag) {
    int f = *dflag;
    size_t idx = (size_t)blockIdx.x * 256 + threadIdx.x;  // over B*CTXLEN*D
    int d = idx & (D - 1);
    size_t rowg = idx >> 9;      // /D
    int p = rowg & (CTXLEN - 1);
    int b = rowg >> 11;          // /CTXLEN
    if (p < M) ctx[idx] = ldf(mems, memOff + ((size_t)b * M + p) * D + d, f);
    else       ctx[idx] = x[((size_t)b * N + (p - M)) * D + d];
}

// ---------------- generic tiled VALU GEMM (fp32-exact fallback + tiny pos GEMM) ----------------
#define BM 64
#define BN 64
#define BK 16
__global__ __launch_bounds__(256) void gemm_kernel(int Mm, int Nn, int Kk,
                                                   const float* __restrict__ A,
                                                   const void* __restrict__ Bw, size_t bwOff,
                                                   const void* __restrict__ bias, size_t biasOff,
                                                   float* __restrict__ C,
                                                   void* __restrict__ Cb,
                                                   int epi,
                                                   const int* __restrict__ dflag) {
    int f = *dflag;
    __shared__ __align__(16) float As[BK][BM + 4];
    __shared__ __align__(16) float Bs[BK][BN + 4];
    int tid = threadIdx.x;
    int bm = blockIdx.y * BM;
    int bn = blockIdx.x * BN;
    int tx = tid & 15, ty = tid >> 4;
    int ka = tid & 15, ma = tid >> 4;   // A loads
    int nb = tid & 63, kb = tid >> 6;   // B loads
    float acc[4][4] = {};
    for (int k0 = 0; k0 < Kk; k0 += BK) {
        #pragma unroll
        for (int p = 0; p < 4; ++p)
            As[ka][ma + 16 * p] = A[(size_t)(bm + ma + 16 * p) * Kk + k0 + ka];
        #pragma unroll
        for (int p = 0; p < 4; ++p)
            Bs[kb + 4 * p][nb] = ldf(Bw, bwOff + (size_t)(k0 + kb + 4 * p) * Nn + bn + nb, f);
        __syncthreads();
        #pragma unroll
        for (int k = 0; k < BK; ++k) {
            float4 a4 = *(const float4*)&As[k][ty * 4];
            float4 b4 = *(const float4*)&Bs[k][tx * 4];
            float a[4] = {a4.x, a4.y, a4.z, a4.w};
            float b[4] = {b4.x, b4.y, b4.z, b4.w};
            #pragma unroll
            for (int i = 0; i < 4; ++i)
                #pragma unroll
                for (int j = 0; j < 4; ++j)
                    acc[i][j] += a[i] * b[j];
        }
        __syncthreads();
    }
    #pragma unroll
    for (int i = 0; i < 4; ++i) {
        int row = bm + ty * 4 + i;
        #pragma unroll
        for (int j = 0; j < 4; ++j) {
            int col = bn + tx * 4 + j;
            float v = acc[i][j];
            if (bias) v += ldf(bias, biasOff + col, f);
            size_t idx = (size_t)row * Nn + col;
            if (epi == 2) v = 0.5f * v * (1.0f + erff(v * 0.70710678118654752f));
            if (Cb) { stf(Cb, idx, f, v); }
            else {
                if (epi == 1) v += C[idx];
                C[idx] = v;
            }
        }
    }
}

// ---------------- MFMA bf16 GEMM: C[M,N] = A[M,K](f32 ws) * B[K,N](weights) + bias ----------------
typedef __attribute__((ext_vector_type(8))) short bfrag;   // 8 bf16 (4 VGPRs)
typedef __attribute__((ext_vector_type(4))) float ffrag;   // 4 f32 accum

__global__ __launch_bounds__(256) void mgemm_kernel(int Mm, int Nn, int Kk,
                                                    const float* __restrict__ A,
                                                    const void* __restrict__ Bw, size_t bwOff,
                                                    const void* __restrict__ bias, size_t biasOff,
                                                    float* __restrict__ C,
                                                    void* __restrict__ Cb,
                                                    int epi,
                                                    const int* __restrict__ dflag) {
    int f = *dflag;
    __shared__ __align__(16) unsigned short As[128][48];   // 12 KB
    __shared__ __align__(16) unsigned short Bs[4096];      // 8 KB, frag-ordered [nb][g][c][e]

    int tid = threadIdx.x;
    int bm = blockIdx.x * 128;
    int bn = blockIdx.y * 128;

    // A staging: thread -> (row, 16-wide k half)
    int arow = tid >> 1;
    int akq  = (tid & 1) * 16;
    // wave/lane decomposition
    int wv = tid >> 6;
    int wr = (wv >> 1) * 64;
    int wc = (wv & 1) * 64;
    int lane = tid & 63;
    int lr = lane & 15;
    int lg = lane >> 4;
    int nbBase = wc >> 4;

    ffrag acc[4][4] = {};

    for (int k0 = 0; k0 < Kk; k0 += 32) {
        // ---- stage A (fp32 -> bf16) ----
        const float* Ar = A + (size_t)(bm + arow) * Kk + k0 + akq;
        #pragma unroll
        for (int c = 0; c < 4; ++c) {
            float4 v = *(const float4*)(Ar + 4 * c);
            ushort4 h;
            h.x = f2bits(v.x); h.y = f2bits(v.y); h.z = f2bits(v.z); h.w = f2bits(v.w);
            *(ushort4*)&As[arow][akq + 4 * c] = h;
        }
        // ---- stage B: vectorized along n, scatter to frag order ----
        #pragma unroll
        for (int cc2 = 0; cc2 < 2; ++cc2) {
            int chunk = tid * 2 + cc2;
            int kr = chunk >> 4;              // 0..31
            int cg = chunk & 15;              // col-group of 8
            int colb = cg * 8;
            unsigned short val[8];
            if (f) {
                const float* src = (const float*)Bw + bwOff + (size_t)(k0 + kr) * Nn + bn + colb;
                float4 v0 = *(const float4*)src;
                float4 v1 = *(const float4*)(src + 4);
                val[0] = f2bits(v0.x); val[1] = f2bits(v0.y);
                val[2] = f2bits(v0.z); val[3] = f2bits(v0.w);
                val[4] = f2bits(v1.x); val[5] = f2bits(v1.y);
                val[6] = f2bits(v1.z); val[7] = f2bits(v1.w);
            } else {
                const unsigned short* src = (const unsigned short*)Bw + bwOff
                                          + (size_t)(k0 + kr) * Nn + bn + colb;
                uint4 u = *(const uint4*)src;
                *(uint4*)val = u;
            }
            int g = kr >> 3, ke = kr & 7;
            int base = (((cg >> 1) * 4 + g) * 16 + 8 * (cg & 1));
            #pragma unroll
            for (int j = 0; j < 8; ++j)
                Bs[(base + j) * 8 + ke] = val[j];
        }
        __syncthreads();
        // ---- fragments + MFMA ----
        bfrag af[4], bfv[4];
        #pragma unroll
        for (int m = 0; m < 4; ++m)
            af[m] = *(const bfrag*)&As[wr + m * 16 + lr][lg * 8];
        #pragma unroll
        for (int n = 0; n < 4; ++n)
            bfv[n] = *(const bfrag*)&Bs[(((nbBase + n) * 4 + lg) * 16 + lr) * 8];
        #pragma unroll
        for (int m = 0; m < 4; ++m)
            #pragma unroll
            for (int n = 0; n < 4; ++n)
                acc[m][n] = __builtin_amdgcn_mfma_f32_16x16x32_bf16(af[m], bfv[n], acc[m][n], 0, 0, 0);
        __syncthreads();
    }
    // ---- epilogue: D layout col=lane&15, row=(lane>>4)*4+j ----
    #pragma unroll
    for (int m = 0; m < 4; ++m) {
        int row0 = bm + wr + m * 16 + lg * 4;
        #pragma unroll
        for (int n = 0; n < 4; ++n) {
            int col = bn + wc + n * 16 + lr;
            float bv = bias ? ldf(bias, biasOff + col, f) : 0.0f;
            #pragma unroll
            for (int j = 0; j < 4; ++j) {
                int row = row0 + j;
                float v = acc[m][n][j] + bv;
                size_t idx = (size_t)row * Nn + col;
                if (epi == 2) v = 0.5f * v * (1.0f + erff(v * 0.70710678118654752f));
                if (Cb) { stf(Cb, idx, f, v); }
                else {
                    if (epi == 1) v += C[idx];
                    C[idx] = v;
                }
            }
        }
    }
}

// ---------------- flash-tiled attention (fp32-exact path, AT=32) ----------------
#define AT 32
#define JT 64
__global__ __launch_bounds__(256) void attn_kernel(const float* __restrict__ q,
                                                   const float* __restrict__ kv,
                                                   const float* __restrict__ pos,
                                                   const float* __restrict__ em,
                                                   float* __restrict__ outp) {
    __shared__ __align__(16) float Qs[AT][68];
    __shared__ __align__(16) float KVs[JT][68];
    __shared__ __align__(16) float Ss[AT][65];
    __shared__ __align__(16) float Ps[95][68];
    __shared__ float gates[M];
    __shared__ float mrow[AT], lrow[AT], arow[AT];

    int t = threadIdx.x;
    int bid = blockIdx.x;
    int raw = bid & 31;
    int it = (raw & 1) ? (31 - (raw >> 1)) : (raw >> 1);
    int h = (bid >> 5) & 7;
    int b = bid >> 8;
    int i0 = it * AT;

    for (int idx = t; idx < AT * 64; idx += 256) {
        int il = idx >> 6, d = idx & 63;
        Qs[il][d] = q[((size_t)(b * N + i0 + il)) * D + h * DH + d];
    }
    for (int idx = t; idx < M; idx += 256) gates[idx] = em[b * M + idx];
    if (t < AT) { mrow[t] = -3e38f; lrow[t] = 0.0f; arow[t] = 0.0f; }

    int ti = t >> 4;
    int tj = t & 15;
    float O[2][4] = {};

    int nx = ((i0 + AT - 1) >> 6) + 1;
    int ntiles = M / JT + nx;
    for (int tile = 0; tile < ntiles; ++tile) {
        int t0 = tile * JT;
        int t0x = t0 - M;
        __syncthreads();
        for (int idx = t; idx < JT * 64; idx += 256) {
            int jl = idx >> 6, d = idx & 63;
            KVs[jl][d] = kv[((size_t)(b * CTXLEN + t0 + jl)) * (2 * D) + h * DH + d];
        }
        int r0 = N - 1 - (i0 + AT - 1) + t0x;
        if (t0x >= 0) {
            for (int idx = t; idx < 95 * 64; idx += 256) {
                int w = idx >> 6, d = idx & 63;
                int r = r0 + w; r = r > (N - 1) ? (N - 1) : r;
                Ps[w][d] = pos[(size_t)r * DH + d];
            }
        }
        __syncthreads();
        float s[2][4] = {};
        #pragma unroll
        for (int d4 = 0; d4 < 16; ++d4) {
            float4 qv[2], kv4[4];
            #pragma unroll
            for (int rr = 0; rr < 2; ++rr) qv[rr] = *(const float4*)&Qs[2 * ti + rr][4 * d4];
            #pragma unroll
            for (int cc = 0; cc < 4; ++cc) kv4[cc] = *(const float4*)&KVs[tj + 16 * cc][4 * d4];
            #pragma unroll
            for (int rr = 0; rr < 2; ++rr)
                #pragma unroll
                for (int cc = 0; cc < 4; ++cc)
                    s[rr][cc] += qv[rr].x * kv4[cc].x + qv[rr].y * kv4[cc].y
                               + qv[rr].z * kv4[cc].z + qv[rr].w * kv4[cc].w;
        }
        if (t0x >= 0) {
            #pragma unroll 4
            for (int d4 = 0; d4 < 16; ++d4) {
                float4 qv[2];
                #pragma unroll
                for (int rr = 0; rr < 2; ++rr) qv[rr] = *(const float4*)&Qs[2 * ti + rr][4 * d4];
                #pragma unroll
                for (int rr = 0; rr < 2; ++rr) {
                    int wb = (AT - 1) - (2 * ti + rr);
                    #pragma unroll
                    for (int cc = 0; cc < 4; ++cc) {
                        float4 pv = *(const float4*)&Ps[tj + 16 * cc + wb][4 * d4];
                        s[rr][cc] += qv[rr].x * pv.x + qv[rr].y * pv.y
                                   + qv[rr].z * pv.z + qv[rr].w * pv.w;
                    }
                }
            }
        }
        #pragma unroll
        for (int rr = 0; rr < 2; ++rr) {
            int il = 2 * ti + rr;
            #pragma unroll
            for (int cc = 0; cc < 4; ++cc) {
                int jl = tj + 16 * cc;
                float v = s[rr][cc] * 0.125f;
                if (t0x >= 0 && (t0x + jl) > (i0 + il)) v = -3e38f;
                Ss[il][jl] = v;
            }
        }
        __syncthreads();
        for (int idx = t; idx < JT * 64; idx += 256) {
            int jl = idx >> 6, d = idx & 63;
            KVs[jl][d] = kv[((size_t)(b * CTXLEN + t0 + jl)) * (2 * D) + D + h * DH + d];
        }
        if (t < AT) {
            int il = t;
            float mo = mrow[il];
            float tmax = -3e38f;
            for (int j = 0; j < JT; ++j) tmax = fmaxf(tmax, Ss[il][j]);
            float mn = fmaxf(mo, tmax);
            float alpha = expf(mo - mn);
            float sum = 0.0f;
            for (int j = 0; j < JT; ++j) {
                float e = expf(Ss[il][j] - mn);
                sum += e;
                int jg = t0 + j;
                float g = (jg < M) ? gates[jg] : 1.0f;
                Ss[il][j] = e * g;
            }
            lrow[il] = lrow[il] * alpha + sum;
            mrow[il] = mn;
            arow[il] = alpha;
        }
        __syncthreads();
        float a0 = arow[2 * ti], a1 = arow[2 * ti + 1];
        #pragma unroll
        for (int dd = 0; dd < 4; ++dd) { O[0][dd] *= a0; O[1][dd] *= a1; }
        #pragma unroll
        for (int jb = 0; jb < 16; ++jb) {
            float4 p0 = *(const float4*)&Ss[2 * ti][4 * jb];
            float4 p1 = *(const float4*)&Ss[2 * ti + 1][4 * jb];
            float4 v0 = *(const float4*)&KVs[4 * jb + 0][4 * tj];
            float4 v1 = *(const float4*)&KVs[4 * jb + 1][4 * tj];
            float4 v2 = *(const float4*)&KVs[4 * jb + 2][4 * tj];
            float4 v3 = *(const float4*)&KVs[4 * jb + 3][4 * tj];
            O[0][0] += p0.x * v0.x + p0.y * v1.x + p0.z * v2.x + p0.w * v3.x;
            O[0][1] += p0.x * v0.y + p0.y * v1.y + p0.z * v2.y + p0.w * v3.y;
            O[0][2] += p0.x * v0.z + p0.y * v1.z + p0.z * v2.z + p0.w * v3.z;
            O[0][3] += p0.x * v0.w + p0.y * v1.w + p0.z * v2.w + p0.w * v3.w;
            O[1][0] += p1.x * v0.x + p1.y * v1.x + p1.z * v2.x + p1.w * v3.x;
            O[1][1] += p1.x * v0.y + p1.y * v1.y + p1.z * v2.y + p1.w * v3.y;
            O[1][2] += p1.x * v0.z + p1.y * v1.z + p1.z * v2.z + p1.w * v3.z;
            O[1][3] += p1.x * v0.w + p1.y * v1.w + p1.z * v2.w + p1.w * v3.w;
        }
    }
    #pragma unroll
    for (int rr = 0; rr < 2; ++rr) {
        int il = 2 * ti + rr;
        float inv = 1.0f / lrow[il];
        float4 r4;
        r4.x = O[rr][0] * inv; r4.y = O[rr][1] * inv;
        r4.z = O[rr][2] * inv; r4.w = O[rr][3] * inv;
        *(float4*)&outp[((size_t)(b * N + i0 + il)) * D + h * DH + 4 * tj] = r4;
    }
}

// ---------------- attention v2 (bf16 path): in-wave softmax, T14 prefetch, j-split ----------------
// launch_bounds(256,4) caps VGPR at the <=128 bucket so LDS (49.6KB) becomes the
// occupancy limit (3 blocks/CU) instead of registers (2 blocks/CU at 148 VGPR).
// x-tile pos-skew is merged into the QK^T d4 loop (shares q loads, shorter live ranges).
#define JSPLIT 2
__global__ __launch_bounds__(256, 4) void attn2_kernel(const float* __restrict__ q,
                                                       const float* __restrict__ kv,
                                                       const float* __restrict__ pos,
                                                       const float* __restrict__ em,
                                                       float* __restrict__ opart,
                                                       float* __restrict__ mlp) {
    __shared__ __align__(16) float          Qs[AT][68];    // 8704 B
    __shared__ __align__(16) unsigned short Kb[JT][72];    // 9216 B
    __shared__ __align__(16) unsigned short Vb[JT][72];    // 9216 B
    __shared__ __align__(16) float          Pw[AT][68];    // 8704 B
    __shared__ __align__(16) unsigned short Psb[95][72];   // 13680 B
    // total 49520 B -> 3 blocks/CU

    int t = threadIdx.x;
    int bid = blockIdx.x;
    int p   = bid & 1;                 // j-split parity
    int raw = (bid >> 1) & 31;
    int it = (raw & 1) ? (31 - (raw >> 1)) : (raw >> 1);
    int h = (bid >> 6) & 7;
    int b = bid >> 9;
    int i0 = it * AT;

    // stage Q (float4)
    for (int idx = t; idx < AT * 16; idx += 256) {
        int il = idx >> 4, d4 = idx & 15;
        *(float4*)&Qs[il][4 * d4] =
            *(const float4*)&q[((size_t)(b * N + i0 + il)) * D + h * DH + 4 * d4];
    }

    int ti = t >> 4;       // 0..15 -> rows 2ti+rr (16 consecutive lanes per row pair)
    int tj = t & 15;       // S col lane / PV d-chunk
    float O[2][4] = {};
    float mo[2] = {-3e38f, -3e38f};
    float lo[2] = {0.0f, 0.0f};

    int nx = ((i0 + AT - 1) >> 6) + 1;
    int ntiles = M / JT + nx;

    // ---- prologue: prefetch first tile's K/V into registers ----
    float4 kpre[4], vpre[4];
    {
        int t0 = p * JT;
        #pragma unroll
        for (int i = 0; i < 4; ++i) {
            int idx = t + i * 256;
            int jl = idx >> 4, d4 = idx & 15;
            const float* base = &kv[(size_t)(b * CTXLEN + t0 + jl) * (2 * D) + h * DH + 4 * d4];
            kpre[i] = *(const float4*)base;
            vpre[i] = *(const float4*)(base + D);
        }
    }

    for (int tile = p; tile < ntiles; tile += JSPLIT) {
        int t0x = tile * JT - M;
        __syncthreads();                 // prev tile's K/V reads complete
        // ---- write prefetched K/V registers to LDS (bf16) ----
        #pragma unroll
        for (int i = 0; i < 4; ++i) {
            int idx = t + i * 256;
            int jl = idx >> 4, d4 = idx & 15;
            ushort4 ku, vu;
            ku.x = f2bits(kpre[i].x); ku.y = f2bits(kpre[i].y);
            ku.z = f2bits(kpre[i].z); ku.w = f2bits(kpre[i].w);
            vu.x = f2bits(vpre[i].x); vu.y = f2bits(vpre[i].y);
            vu.z = f2bits(vpre[i].z); vu.w = f2bits(vpre[i].w);
            *(ushort4*)&Kb[jl][4 * d4] = ku;
            *(ushort4*)&Vb[jl][4 * d4] = vu;
        }
        // ---- stage pos window (bf16, vectorized) for x-tiles ----
        if (t0x >= 0) {
            int r0 = N - 1 - (i0 + AT - 1) + t0x;
            for (int idx = t; idx < 95 * 8; idx += 256) {
                int w = idx >> 3, c = idx & 7;
                int r = r0 + w; r = r > (N - 1) ? (N - 1) : r;
                const float* pp = &pos[(size_t)r * DH + 8 * c];
                float4 a = *(const float4*)pp;
                float4 bb = *(const float4*)(pp + 4);
                ushort4 u0, u1;
                u0.x = f2bits(a.x);  u0.y = f2bits(a.y);  u0.z = f2bits(a.z);  u0.w = f2bits(a.w);
                u1.x = f2bits(bb.x); u1.y = f2bits(bb.y); u1.z = f2bits(bb.z); u1.w = f2bits(bb.w);
                *(ushort4*)&Psb[w][8 * c]     = u0;
                *(ushort4*)&Psb[w][8 * c + 4] = u1;
            }
        }
        __syncthreads();                 // K/V/Ps ready
        // ---- issue NEXT tile's K/V loads (latency hides under compute) ----
        if (tile + JSPLIT < ntiles) {
            int t0n = (tile + JSPLIT) * JT;
            #pragma unroll
            for (int i = 0; i < 4; ++i) {
                int idx = t + i * 256;
                int jl = idx >> 4, d4 = idx & 15;
                const float* base = &kv[(size_t)(b * CTXLEN + t0n + jl) * (2 * D) + h * DH + 4 * d4];
                kpre[i] = *(const float4*)base;
                vpre[i] = *(const float4*)(base + D);
            }
        }
        // ---- S = Q K^T (+ pos skew merged for x-tiles: shared q loads) ----
        float s[2][4] = {};
        if (t0x >= 0) {
            int wb0 = (AT - 1) - 2 * ti;
            int wb1 = wb0 - 1;
            #pragma unroll 4
            for (int d4 = 0; d4 < 16; ++d4) {
                float4 q0 = *(const float4*)&Qs[2 * ti][4 * d4];
                float4 q1 = *(const float4*)&Qs[2 * ti + 1][4 * d4];
                #pragma unroll
                for (int cc = 0; cc < 4; ++cc) {
                    float4 kf = us4f(*(const ushort4*)&Kb[tj + 16 * cc][4 * d4]);
                    s[0][cc] += q0.x * kf.x + q0.y * kf.y + q0.z * kf.z + q0.w * kf.w;
                    s[1][cc] += q1.x * kf.x + q1.y * kf.y + q1.z * kf.z + q1.w * kf.w;
                    float4 p0 = us4f(*(const ushort4*)&Psb[tj + 16 * cc + wb0][4 * d4]);
                    float4 p1 = us4f(*(const ushort4*)&Psb[tj + 16 * cc + wb1][4 * d4]);
                    s[0][cc] += q0.x * p0.x + q0.y * p0.y + q0.z * p0.z + q0.w * p0.w;
                    s[1][cc] += q1.x * p1.x + q1.y * p1.y + q1.z * p1.z + q1.w * p1.w;
                }
            }
        } else {
            #pragma unroll
            for (int d4 = 0; d4 < 16; ++d4) {
                float4 q0 = *(const float4*)&Qs[2 * ti][4 * d4];
                float4 q1 = *(const float4*)&Qs[2 * ti + 1][4 * d4];
                #pragma unroll
                for (int cc = 0; cc < 4; ++cc) {
                    float4 kf = us4f(*(const ushort4*)&Kb[tj + 16 * cc][4 * d4]);
                    s[0][cc] += q0.x * kf.x + q0.y * kf.y + q0.z * kf.z + q0.w * kf.w;
                    s[1][cc] += q1.x * kf.x + q1.y * kf.y + q1.z * kf.z + q1.w * kf.w;
                }
            }
        }
        // ---- scale + causal mask ----
        #pragma unroll
        for (int rr = 0; rr < 2; ++rr) {
            int il = 2 * ti + rr;
            #pragma unroll
            for (int cc = 0; cc < 4; ++cc) {
                float v = s[rr][cc] * 0.125f;
                int jl = tj + 16 * cc;
                if (t0x >= 0 && (t0x + jl) > (i0 + il)) v = -3e38f;
                s[rr][cc] = v;
            }
        }
        // ---- gates (global, L1-broadcast) ----
        float g4[4];
        #pragma unroll
        for (int cc = 0; cc < 4; ++cc) {
            int jg = tile * JT + tj + 16 * cc;
            g4[cc] = (jg < M) ? em[b * M + jg] : 1.0f;
        }
        // ---- in-wave online softmax (width-16 shuffles; rows live in 16-lane groups) ----
        #pragma unroll
        for (int rr = 0; rr < 2; ++rr) {
            float tmax = fmaxf(fmaxf(s[rr][0], s[rr][1]), fmaxf(s[rr][2], s[rr][3]));
            tmax = fmaxf(tmax, __shfl_xor(tmax, 8, 16));
            tmax = fmaxf(tmax, __shfl_xor(tmax, 4, 16));
            tmax = fmaxf(tmax, __shfl_xor(tmax, 2, 16));
            tmax = fmaxf(tmax, __shfl_xor(tmax, 1, 16));
            float mn = fmaxf(mo[rr], tmax);
            float al = __expf(mo[rr] - mn);
            mo[rr] = mn;
            float sum = 0.0f;
            float pv4[4];
            #pragma unroll
            for (int cc = 0; cc < 4; ++cc) {
                float e = __expf(s[rr][cc] - mn);
                sum += e;
                pv4[cc] = e * g4[cc];
            }
            sum += __shfl_xor(sum, 8, 16);
            sum += __shfl_xor(sum, 4, 16);
            sum += __shfl_xor(sum, 2, 16);
            sum += __shfl_xor(sum, 1, 16);
            lo[rr] = lo[rr] * al + sum;
            #pragma unroll
            for (int dd = 0; dd < 4; ++dd) O[rr][dd] *= al;
            int il = 2 * ti + rr;
            #pragma unroll
            for (int cc = 0; cc < 4; ++cc) Pw[il][tj + 16 * cc] = pv4[cc];
        }
        // ---- PV (P rows written by this wave; wave64 lockstep -> no barrier) ----
        #pragma unroll
        for (int jb = 0; jb < 16; ++jb) {
            float4 p0 = *(const float4*)&Pw[2 * ti][4 * jb];
            float4 p1 = *(const float4*)&Pw[2 * ti + 1][4 * jb];
            float4 v0 = us4f(*(const ushort4*)&Vb[4 * jb + 0][4 * tj]);
            float4 v1 = us4f(*(const ushort4*)&Vb[4 * jb + 1][4 * tj]);
            float4 v2 = us4f(*(const ushort4*)&Vb[4 * jb + 2][4 * tj]);
            float4 v3 = us4f(*(const ushort4*)&Vb[4 * jb + 3][4 * tj]);
            O[0][0] += p0.x * v0.x + p0.y * v1.x + p0.z * v2.x + p0.w * v3.x;
            O[0][1] += p0.x * v0.y + p0.y * v1.y + p0.z * v2.y + p0.w * v3.y;
            O[0][2] += p0.x * v0.z + p0.y * v1.z + p0.z * v2.z + p0.w * v3.z;
            O[0][3] += p0.x * v0.w + p0.y * v1.w + p0.z * v2.w + p0.w * v3.w;
            O[1][0] += p1.x * v0.x + p1.y * v1.x + p1.z * v2.x + p1.w * v3.x;
            O[1][1] += p1.x * v0.y + p1.y * v1.y + p1.z * v2.y + p1.w * v3.y;
            O[1][2] += p1.x * v0.z + p1.y * v1.z + p1.z * v2.z + p1.w * v3.z;
            O[1][3] += p1.x * v0.w + p1.y * v1.w + p1.z * v2.w + p1.w * v3.w;
        }
    }
    // ---- write unnormalized partials + (m,l) ----
    size_t ob = ((size_t)((p * BATCH + b) * H + h) * N + i0) * DH;
    #pragma unroll
    for (int rr = 0; rr < 2; ++rr) {
        int il = 2 * ti + rr;
        float4 r4;
        r4.x = O[rr][0]; r4.y = O[rr][1]; r4.z = O[rr][2]; r4.w = O[rr][3];
        *(float4*)&opart[ob + (size_t)il * DH + 4 * tj] = r4;
        if (tj == 0) {
            size_t mlIdx = (((size_t)(p * BATCH + b) * H + h) * N + i0 + il) * 2;
            mlp[mlIdx]     = mo[rr];
            mlp[mlIdx + 1] = lo[rr];
        }
    }
}

// ---------------- combine j-split partials ----------------
__global__ __launch_bounds__(256) void attn_combine_kernel(const float* __restrict__ opart,
                                                           const float* __restrict__ mlp,
                                                           float* __restrict__ aout) {
    int row = blockIdx.x;            // b*N + i
    int b = row >> 10;
    int i = row & (N - 1);
    for (int d = threadIdx.x; d < D; d += 256) {
        int h = d >> 6, dd = d & 63;
        size_t s0 = ((size_t)(b * H + h) * N + i);
        size_t s1 = ((size_t)((BATCH + b) * H + h) * N + i);
        float m0 = mlp[s0 * 2], l0 = mlp[s0 * 2 + 1];
        float m1 = mlp[s1 * 2], l1 = mlp[s1 * 2 + 1];
        float m = fmaxf(m0, m1);
        float w0 = __expf(m0 - m), w1 = __expf(m1 - m);
        float denom = l0 * w0 + l1 * w1;
        aout[(size_t)row * D + d] = (opart[s0 * DH + dd] * w0 + opart[s1 * DH + dd] * w1) / denom;
    }
}

// ---------------- final layernorm ----------------
__global__ __launch_bounds__(256) void ln_kernel(const float* __restrict__ x,
                                                 const void* __restrict__ g,
                                                 const void* __restrict__ bta,
                                                 float* __restrict__ y,
                                                 const int* __restrict__ dflag) {
    int f = *dflag;
    int row = blockIdx.x;
    const float* xr = x + (size_t)row * D;
    __shared__ float red[4];
    int lane = threadIdx.x & 63, wv = threadIdx.x >> 6;
    float s = 0.0f;
    for (int d = threadIdx.x; d < D; d += 256) s += xr[d];
    #pragma unroll
    for (int off = 32; off > 0; off >>= 1) s += __shfl_xor(s, off, 64);
    if (lane == 0) red[wv] = s;
    __syncthreads();
    float mu = (red[0] + red[1] + red[2] + red[3]) * (1.0f / D);
    __syncthreads();
    float v = 0.0f;
    for (int d = threadIdx.x; d < D; d += 256) { float tt = xr[d] - mu; v += tt * tt; }
    #pragma unroll
    for (int off = 32; off > 0; off >>= 1) v += __shfl_xor(v, off, 64);
    if (lane == 0) red[wv] = v;
    __syncthreads();
    float var = (red[0] + red[1] + red[2] + red[3]) * (1.0f / D);
    float rstd = 1.0f / sqrtf(var + 1e-5f);
    for (int d = threadIdx.x; d < D; d += 256)
        y[(size_t)row * D + d] = (xr[d] - mu) * rstd * ldf(g, d, f) + ldf(bta, d, f);
}

// ---------------- aux write ----------------
__global__ void write_aux_kernel(const float* __restrict__ aux, void* __restrict__ out,
                                 const int* __restrict__ dflag) {
    int f = *dflag;
    if (threadIdx.x < BATCH)
        stf(out, (size_t)ROWS * V + threadIdx.x, f, aux[threadIdx.x]);
}

extern "C" void kernel_launch(void* const* d_in, const int* in_sizes, int n_in,
                              void* d_out, int out_size, void* d_ws, size_t ws_size,
                              hipStream_t stream) {
    (void)n_in; (void)out_size; (void)ws_size;
    const int*  tokens  = (const int*)d_in[0];
    const void* mems    = d_in[1];
    const int*  times   = (const int*)d_in[2];
    const void* tok_emb = d_in[3];
    const void* Wq   = d_in[4];
    const void* bq   = d_in[5];
    const void* Wkv  = d_in[6];
    const void* bkv  = d_in[7];
    const void* Wo   = d_in[8];
    const void* bo   = d_in[9];
    const void* Wpos = d_in[10];
    const void* bpos = d_in[11];
    const void* Wexp = d_in[12];
    const void* bexp = d_in[13];
    const void* W1   = d_in[14];
    const void* b1   = d_in[15];
    const void* W2   = d_in[16];
    const void* b2v  = d_in[17];
    const void* ln_g = d_in[18];
    const void* ln_b = d_in[19];
    const void* Whead= d_in[20];

    float* ws  = (float*)d_ws;
    float* x    = ws;                            // ROWS*D
    float* pe   = x    + (size_t)ROWS * D;       // N*D
    float* ctx  = pe   + (size_t)N * D;          // CROWS*D   (y, opart alias)
    float* kv   = ctx  + (size_t)CROWS * D;      // CROWS*2D  (h1 aliases)
    float* q    = kv   + (size_t)CROWS * 2 * D;  // ROWS*D
    float* pos  = q    + (size_t)ROWS * D;       // N*DH
    float* em   = pos  + (size_t)N * DH;         // B*M
    float* aout = em   + (size_t)BATCH * M;      // ROWS*D
    float* aux  = aout + (size_t)ROWS * D;       // 2 floats + flag
    int*   flag = (int*)(aux + 2);
    float* mlp  = aux + 16;                      // JSPLIT*B*H*N*2 = 65,536 floats
    float* h1   = kv;   // alias
    float* y    = ctx;  // alias
    float* opart = ctx; // alias: CROWS*D == JSPLIT*B*H*N*DH floats; ctx dead during attn

    // Host-side dtype guess from staged byte size of tok_emb (V*D elems).
    int hf32 = (in_sizes && in_sizes[3] >= (int)(V * (size_t)D * 3)) ? 1 : 0;

    detect_kernel<<<1, 256, 0, stream>>>(tok_emb, flag, aux);
    embed_kernel<<<ROWS, 256, 0, stream>>>(tokens, tok_emb, x, flag);
    pe_kernel<<<N, 256, 0, stream>>>(pe);

    for (int l = 0; l < DEPTH; ++l) {
        expire_kernel<<<(BATCH * M) / 4, 256, 0, stream>>>(
            mems, (size_t)l * BATCH * M * D, times + (size_t)l * BATCH * M,
            Wexp, (size_t)l * D, bexp, (size_t)l, em, aux, flag);
        ctx_kernel<<<(BATCH * CTXLEN * D) / 256, 256, 0, stream>>>(
            mems, (size_t)l * BATCH * M * D, x, ctx, flag);
        if (hf32) {
            gemm_kernel<<<dim3(D / BN, ROWS / BM), 256, 0, stream>>>(
                ROWS, D, D, x, Wq, (size_t)l * D * D, bq, (size_t)l * D, q, nullptr, 0, flag);
            gemm_kernel<<<dim3(2 * D / BN, CROWS / BM), 256, 0, stream>>>(
                CROWS, 2 * D, D, ctx, Wkv, (size_t)l * D * 2 * D, bkv, (size_t)l * 2 * D, kv, nullptr, 0, flag);
        } else {
            mgemm_kernel<<<dim3(ROWS / 128, D / 128), 256, 0, stream>>>(
                ROWS, D, D, x, Wq, (size_t)l * D * D, bq, (size_t)l * D, q, nullptr, 0, flag);
            mgemm_kernel<<<dim3(CROWS / 128, 2 * D / 128), 256, 0, stream>>>(
                CROWS, 2 * D, D, ctx, Wkv, (size_t)l * D * 2 * D, bkv, (size_t)l * 2 * D, kv, nullptr, 0, flag);
        }
        gemm_kernel<<<dim3(DH / BN, N / BM), 256, 0, stream>>>(
            N, DH, D, pe, Wpos, (size_t)l * D * DH, bpos, (size_t)l * DH, pos, nullptr, 0, flag);
        if (hf32) {
            attn_kernel<<<BATCH * H * (N / AT), 256, 0, stream>>>(q, kv, pos, em, aout);
        } else {
            attn2_kernel<<<BATCH * H * (N / AT) * JSPLIT, 256, 0, stream>>>(q, kv, pos, em, opart, mlp);
            attn_combine_kernel<<<ROWS, 256, 0, stream>>>(opart, mlp, aout);
        }
        if (hf32) {
            gemm_kernel<<<dim3(D / BN, ROWS / BM), 256, 0, stream>>>(
                ROWS, D, D, aout, Wo, (size_t)l * D * D, bo, (size_t)l * D, x, nullptr, 1, flag);
            gemm_kernel<<<dim3(4 * D / BN, ROWS / BM), 256, 0, stream>>>(
                ROWS, 4 * D, D, x, W1, (size_t)l * D * 4 * D, b1, (size_t)l * 4 * D, h1, nullptr, 2, flag);
            gemm_kernel<<<dim3(D / BN, ROWS / BM), 256, 0, stream>>>(
                ROWS, D, 4 * D, h1, W2, (size_t)l * 4 * D * D, b2v, (size_t)l * D, x, nullptr, 1, flag);
        } else {
            mgemm_kernel<<<dim3(ROWS / 128, D / 128), 256, 0, stream>>>(
                ROWS, D, D, aout, Wo, (size_t)l * D * D, bo, (size_t)l * D, x, nullptr, 1, flag);
            mgemm_kernel<<<dim3(ROWS / 128, 4 * D / 128), 256, 0, stream>>>(
                ROWS, 4 * D, D, x, W1, (size_t)l * D * 4 * D, b1, (size_t)l * 4 * D, h1, nullptr, 2, flag);
            mgemm_kernel<<<dim3(ROWS / 128, D / 128), 256, 0, stream>>>(
                ROWS, D, 4 * D, h1, W2, (size_t)l * 4 * D * D, b2v, (size_t)l * D, x, nullptr, 1, flag);
        }
    }

    ln_kernel<<<ROWS, 256, 0, stream>>>(x, ln_g, ln_b, y, flag);
    if (hf32) {
        gemm_kernel<<<dim3(V / BN, ROWS / BM), 256, 0, stream>>>(
            ROWS, V, D, y, Whead, 0, nullptr, 0, nullptr, d_out, 0, flag);
    } else {
        mgemm_kernel<<<dim3(ROWS / 128, V / 128), 256, 0, stream>>>(
            ROWS, V, D, y, Whead, 0, nullptr, 0, nullptr, d_out, 0, flag);
    }
    write_aux_kernel<<<1, 64, 0, stream>>>(aux, d_out, flag);
}

// Round 14
// 2306.963 us; speedup vs baseline: 1.6200x; 1.4730x over previous
//
#include <hip/hip_runtime.h>
#include <hip/hip_bf16.h>
#include <math.h>

// Problem constants
#define DEPTH 4
#define D 512
#define H 8
#define DH 64
#define N 1024
#define M 1024
#define V 32000
#define BATCH 2
#define CTXLEN (M + N)         // 2048
#define ROWS (BATCH * N)       // 2048
#define CROWS (BATCH * CTXLEN) // 4096

typedef __hip_bfloat16 bf16;

static __device__ __forceinline__ float b2f(bf16 v) { return __bfloat162float(v); }

// dtype-agnostic load/store: f==1 -> fp32, f==0 -> bf16
static __device__ __forceinline__ float ldf(const void* p, size_t i, int f) {
    return f ? ((const float*)p)[i] : b2f(((const bf16*)p)[i]);
}
static __device__ __forceinline__ void stf(void* p, size_t i, int f, float v) {
    if (f) ((float*)p)[i] = v;
    else   ((bf16*)p)[i] = __float2bfloat16(v);
}
static __device__ __forceinline__ unsigned short f2bits(float v) {
    union { bf16 b; unsigned short u; } cv;
    cv.b = __float2bfloat16(v);
    return cv.u;
}
static __device__ __forceinline__ unsigned short ldbits(const void* p, size_t i, int f) {
    if (f) return f2bits(((const float*)p)[i]);
    return ((const unsigned short*)p)[i];
}
static __device__ __forceinline__ float us2f(unsigned short u) {
    union { float f; unsigned int i; } c;
    c.i = ((unsigned int)u) << 16;
    return c.f;
}
static __device__ __forceinline__ float4 us4f(ushort4 u) {
    float4 r;
    r.x = us2f(u.x); r.y = us2f(u.y); r.z = us2f(u.z); r.w = us2f(u.w);
    return r;
}

// ---------------- dtype detection (device-side, used for data reads) ----------------
__global__ void detect_kernel(const void* __restrict__ p, int* __restrict__ flag,
                              float* __restrict__ aux) {
    __shared__ int cnt;
    if (threadIdx.x == 0) cnt = 0;
    __syncthreads();
    int bad = 0;
    for (int i = threadIdx.x; i < 1024; i += 256) {
        float v = b2f(((const bf16*)p)[i]);
        if (!(fabsf(v) < 16.0f)) bad++;   // NaN also counts as bad
    }
    if (bad) atomicAdd(&cnt, bad);
    __syncthreads();
    if (threadIdx.x == 0) *flag = (cnt >= 8) ? 1 : 0;
    if (threadIdx.x < BATCH) aux[threadIdx.x] = 0.0f;
}

// ---------------- embedding ----------------
__global__ __launch_bounds__(256) void embed_kernel(const int* __restrict__ tokens,
                                                    const void* __restrict__ emb,
                                                    float* __restrict__ x,
                                                    const int* __restrict__ dflag) {
    int f = *dflag;
    int row = blockIdx.x;                 // b*N + i
    int tok = tokens[row];
    float* xr = x + (size_t)row * D;
    for (int d = threadIdx.x; d < D; d += 256)
        xr[d] = ldf(emb, (size_t)tok * D + d, f);
}

// ---------------- sinusoidal embedding table ----------------
__global__ __launch_bounds__(256) void pe_kernel(float* __restrict__ pe) {
    int r = blockIdx.x;
    int k = threadIdx.x;                  // 0..255 (freq index)
    float t = (float)(N - 1 - r);
    float inv = expf(-(float)k * (9.210340371976184f / 256.0f)); // 10000^{-k/256}
    float s = t * inv;
    pe[(size_t)r * D + k]       = sinf(s);
    pe[(size_t)r * D + 256 + k] = cosf(s);
}

// ---------------- expire span gating (per layer) ----------------
__global__ __launch_bounds__(256) void expire_kernel(const void* __restrict__ mems,
                                                     size_t memOff,
                                                     const int* __restrict__ times_l,
                                                     const void* __restrict__ Wexp,
                                                     size_t wOff,
                                                     const void* __restrict__ bexp,
                                                     size_t bOff,
                                                     float* __restrict__ em,
                                                     float* __restrict__ aux,
                                                     const int* __restrict__ dflag) {
    int f = *dflag;
    int wave = (blockIdx.x * 256 + threadIdx.x) >> 6;  // global j over B*M
    int lane = threadIdx.x & 63;
    int b = wave / M, j = wave % M;
    size_t rbase = memOff + ((size_t)b * M + j) * D;
    float s = 0.0f;
    for (int d = lane; d < D; d += 64)
        s += ldf(mems, rbase + d, f) * ldf(Wexp, wOff + d, f);
    #pragma unroll
    for (int off = 32; off > 0; off >>= 1) s += __shfl_xor(s, off, 64);
    if (lane == 0) {
        s += ldf(bexp, bOff, f);
        float e = 1024.0f / (1.0f + expf(-s));      // sigmoid * MAXMEM
        float t = (float)times_l[b * M + j];
        float emv = (e - t) * (1.0f / 128.0f) + 1.0f;
        emv = fminf(fmaxf(emv, 0.0f), 1.0f);
        em[b * M + j] = emv;
        if (emv > 0.0f && emv < 1.0f)
            atomicAdd(&aux[b], e * (1.0f / (128.0f * 1024.0f)));
    }
}

// ---------------- ctx = concat(mem, x) fp32 ----------------
__global__ __launch_bounds__(256) void ctx_kernel(const void* __restrict__ mems,
                                                  size_t memOff,
                                                  const float* __restrict__ x,
                                                  float* __restrict__ ctx,
                                                  const int* __restrict__ dflag) {
    int f = *dflag;
    size_t idx = (size_t)blockIdx.x * 256 + threadIdx.x;  // over B*CTXLEN*D
    int d = idx & (D - 1);
    size_t rowg = idx >> 9;      // /D
    int p = rowg & (CTXLEN - 1);
    int b = rowg >> 11;          // /CTXLEN
    if (p < M) ctx[idx] = ldf(mems, memOff + ((size_t)b * M + p) * D + d, f);
    else       ctx[idx] = x[((size_t)b * N + (p - M)) * D + d];
}

// ---------------- generic tiled VALU GEMM (fp32-exact fallback + tiny pos GEMM) ----------------
#define BM 64
#define BN 64
#define BK 16
__global__ __launch_bounds__(256) void gemm_kernel(int Mm, int Nn, int Kk,
                                                   const float* __restrict__ A,
                                                   const void* __restrict__ Bw, size_t bwOff,
                                                   const void* __restrict__ bias, size_t biasOff,
                                                   float* __restrict__ C,
                                                   void* __restrict__ Cb,
                                                   int epi,
                                                   const int* __restrict__ dflag) {
    int f = *dflag;
    __shared__ __align__(16) float As[BK][BM + 4];
    __shared__ __align__(16) float Bs[BK][BN + 4];
    int tid = threadIdx.x;
    int bm = blockIdx.y * BM;
    int bn = blockIdx.x * BN;
    int tx = tid & 15, ty = tid >> 4;
    int ka = tid & 15, ma = tid >> 4;   // A loads
    int nb = tid & 63, kb = tid >> 6;   // B loads
    float acc[4][4] = {};
    for (int k0 = 0; k0 < Kk; k0 += BK) {
        #pragma unroll
        for (int p = 0; p < 4; ++p)
            As[ka][ma + 16 * p] = A[(size_t)(bm + ma + 16 * p) * Kk + k0 + ka];
        #pragma unroll
        for (int p = 0; p < 4; ++p)
            Bs[kb + 4 * p][nb] = ldf(Bw, bwOff + (size_t)(k0 + kb + 4 * p) * Nn + bn + nb, f);
        __syncthreads();
        #pragma unroll
        for (int k = 0; k < BK; ++k) {
            float4 a4 = *(const float4*)&As[k][ty * 4];
            float4 b4 = *(const float4*)&Bs[k][tx * 4];
            float a[4] = {a4.x, a4.y, a4.z, a4.w};
            float b[4] = {b4.x, b4.y, b4.z, b4.w};
            #pragma unroll
            for (int i = 0; i < 4; ++i)
                #pragma unroll
                for (int j = 0; j < 4; ++j)
                    acc[i][j] += a[i] * b[j];
        }
        __syncthreads();
    }
    #pragma unroll
    for (int i = 0; i < 4; ++i) {
        int row = bm + ty * 4 + i;
        #pragma unroll
        for (int j = 0; j < 4; ++j) {
            int col = bn + tx * 4 + j;
            float v = acc[i][j];
            if (bias) v += ldf(bias, biasOff + col, f);
            size_t idx = (size_t)row * Nn + col;
            if (epi == 2) v = 0.5f * v * (1.0f + erff(v * 0.70710678118654752f));
            if (Cb) { stf(Cb, idx, f, v); }
            else {
                if (epi == 1) v += C[idx];
                C[idx] = v;
            }
        }
    }
}

// ---------------- MFMA bf16 GEMM: C[M,N] = A[M,K](f32 ws) * B[K,N](weights) + bias ----------------
typedef __attribute__((ext_vector_type(8))) short bfrag;   // 8 bf16 (4 VGPRs)
typedef __attribute__((ext_vector_type(4))) float ffrag;   // 4 f32 accum

__global__ __launch_bounds__(256) void mgemm_kernel(int Mm, int Nn, int Kk,
                                                    const float* __restrict__ A,
                                                    const void* __restrict__ Bw, size_t bwOff,
                                                    const void* __restrict__ bias, size_t biasOff,
                                                    float* __restrict__ C,
                                                    void* __restrict__ Cb,
                                                    int epi,
                                                    const int* __restrict__ dflag) {
    int f = *dflag;
    __shared__ __align__(16) unsigned short As[128][48];   // 12 KB
    __shared__ __align__(16) unsigned short Bs[4096];      // 8 KB, frag-ordered [nb][g][c][e]

    int tid = threadIdx.x;
    int bm = blockIdx.x * 128;
    int bn = blockIdx.y * 128;

    // A staging: thread -> (row, 16-wide k half)
    int arow = tid >> 1;
    int akq  = (tid & 1) * 16;
    // wave/lane decomposition
    int wv = tid >> 6;
    int wr = (wv >> 1) * 64;
    int wc = (wv & 1) * 64;
    int lane = tid & 63;
    int lr = lane & 15;
    int lg = lane >> 4;
    int nbBase = wc >> 4;

    ffrag acc[4][4] = {};

    for (int k0 = 0; k0 < Kk; k0 += 32) {
        // ---- stage A (fp32 -> bf16) ----
        const float* Ar = A + (size_t)(bm + arow) * Kk + k0 + akq;
        #pragma unroll
        for (int c = 0; c < 4; ++c) {
            float4 v = *(const float4*)(Ar + 4 * c);
            ushort4 h;
            h.x = f2bits(v.x); h.y = f2bits(v.y); h.z = f2bits(v.z); h.w = f2bits(v.w);
            *(ushort4*)&As[arow][akq + 4 * c] = h;
        }
        // ---- stage B: vectorized along n, scatter to frag order ----
        #pragma unroll
        for (int cc2 = 0; cc2 < 2; ++cc2) {
            int chunk = tid * 2 + cc2;
            int kr = chunk >> 4;              // 0..31
            int cg = chunk & 15;              // col-group of 8
            int colb = cg * 8;
            unsigned short val[8];
            if (f) {
                const float* src = (const float*)Bw + bwOff + (size_t)(k0 + kr) * Nn + bn + colb;
                float4 v0 = *(const float4*)src;
                float4 v1 = *(const float4*)(src + 4);
                val[0] = f2bits(v0.x); val[1] = f2bits(v0.y);
                val[2] = f2bits(v0.z); val[3] = f2bits(v0.w);
                val[4] = f2bits(v1.x); val[5] = f2bits(v1.y);
                val[6] = f2bits(v1.z); val[7] = f2bits(v1.w);
            } else {
                const unsigned short* src = (const unsigned short*)Bw + bwOff
                                          + (size_t)(k0 + kr) * Nn + bn + colb;
                uint4 u = *(const uint4*)src;
                *(uint4*)val = u;
            }
            int g = kr >> 3, ke = kr & 7;
            int base = (((cg >> 1) * 4 + g) * 16 + 8 * (cg & 1));
            #pragma unroll
            for (int j = 0; j < 8; ++j)
                Bs[(base + j) * 8 + ke] = val[j];
        }
        __syncthreads();
        // ---- fragments + MFMA ----
        bfrag af[4], bfv[4];
        #pragma unroll
        for (int m = 0; m < 4; ++m)
            af[m] = *(const bfrag*)&As[wr + m * 16 + lr][lg * 8];
        #pragma unroll
        for (int n = 0; n < 4; ++n)
            bfv[n] = *(const bfrag*)&Bs[(((nbBase + n) * 4 + lg) * 16 + lr) * 8];
        #pragma unroll
        for (int m = 0; m < 4; ++m)
            #pragma unroll
            for (int n = 0; n < 4; ++n)
                acc[m][n] = __builtin_amdgcn_mfma_f32_16x16x32_bf16(af[m], bfv[n], acc[m][n], 0, 0, 0);
        __syncthreads();
    }
    // ---- epilogue: D layout col=lane&15, row=(lane>>4)*4+j ----
    #pragma unroll
    for (int m = 0; m < 4; ++m) {
        int row0 = bm + wr + m * 16 + lg * 4;
        #pragma unroll
        for (int n = 0; n < 4; ++n) {
            int col = bn + wc + n * 16 + lr;
            float bv = bias ? ldf(bias, biasOff + col, f) : 0.0f;
            #pragma unroll
            for (int j = 0; j < 4; ++j) {
                int row = row0 + j;
                float v = acc[m][n][j] + bv;
                size_t idx = (size_t)row * Nn + col;
                if (epi == 2) v = 0.5f * v * (1.0f + erff(v * 0.70710678118654752f));
                if (Cb) { stf(Cb, idx, f, v); }
                else {
                    if (epi == 1) v += C[idx];
                    C[idx] = v;
                }
            }
        }
    }
}

// ---------------- flash-tiled attention (fp32-exact path, AT=32) ----------------
#define AT 32
#define JT 64
__global__ __launch_bounds__(256) void attn_kernel(const float* __restrict__ q,
                                                   const float* __restrict__ kv,
                                                   const float* __restrict__ pos,
                                                   const float* __restrict__ em,
                                                   float* __restrict__ outp) {
    __shared__ __align__(16) float Qs[AT][68];
    __shared__ __align__(16) float KVs[JT][68];
    __shared__ __align__(16) float Ss[AT][65];
    __shared__ __align__(16) float Ps[95][68];
    __shared__ float gates[M];
    __shared__ float mrow[AT], lrow[AT], arow[AT];

    int t = threadIdx.x;
    int bid = blockIdx.x;
    int raw = bid & 31;
    int it = (raw & 1) ? (31 - (raw >> 1)) : (raw >> 1);
    int h = (bid >> 5) & 7;
    int b = bid >> 8;
    int i0 = it * AT;

    for (int idx = t; idx < AT * 64; idx += 256) {
        int il = idx >> 6, d = idx & 63;
        Qs[il][d] = q[((size_t)(b * N + i0 + il)) * D + h * DH + d];
    }
    for (int idx = t; idx < M; idx += 256) gates[idx] = em[b * M + idx];
    if (t < AT) { mrow[t] = -3e38f; lrow[t] = 0.0f; arow[t] = 0.0f; }

    int ti = t >> 4;
    int tj = t & 15;
    float O[2][4] = {};

    int nx = ((i0 + AT - 1) >> 6) + 1;
    int ntiles = M / JT + nx;
    for (int tile = 0; tile < ntiles; ++tile) {
        int t0 = tile * JT;
        int t0x = t0 - M;
        __syncthreads();
        for (int idx = t; idx < JT * 64; idx += 256) {
            int jl = idx >> 6, d = idx & 63;
            KVs[jl][d] = kv[((size_t)(b * CTXLEN + t0 + jl)) * (2 * D) + h * DH + d];
        }
        int r0 = N - 1 - (i0 + AT - 1) + t0x;
        if (t0x >= 0) {
            for (int idx = t; idx < 95 * 64; idx += 256) {
                int w = idx >> 6, d = idx & 63;
                int r = r0 + w; r = r > (N - 1) ? (N - 1) : r;
                Ps[w][d] = pos[(size_t)r * DH + d];
            }
        }
        __syncthreads();
        float s[2][4] = {};
        #pragma unroll
        for (int d4 = 0; d4 < 16; ++d4) {
            float4 qv[2], kv4[4];
            #pragma unroll
            for (int rr = 0; rr < 2; ++rr) qv[rr] = *(const float4*)&Qs[2 * ti + rr][4 * d4];
            #pragma unroll
            for (int cc = 0; cc < 4; ++cc) kv4[cc] = *(const float4*)&KVs[tj + 16 * cc][4 * d4];
            #pragma unroll
            for (int rr = 0; rr < 2; ++rr)
                #pragma unroll
                for (int cc = 0; cc < 4; ++cc)
                    s[rr][cc] += qv[rr].x * kv4[cc].x + qv[rr].y * kv4[cc].y
                               + qv[rr].z * kv4[cc].z + qv[rr].w * kv4[cc].w;
        }
        if (t0x >= 0) {
            #pragma unroll 4
            for (int d4 = 0; d4 < 16; ++d4) {
                float4 qv[2];
                #pragma unroll
                for (int rr = 0; rr < 2; ++rr) qv[rr] = *(const float4*)&Qs[2 * ti + rr][4 * d4];
                #pragma unroll
                for (int rr = 0; rr < 2; ++rr) {
                    int wb = (AT - 1) - (2 * ti + rr);
                    #pragma unroll
                    for (int cc = 0; cc < 4; ++cc) {
                        float4 pv = *(const float4*)&Ps[tj + 16 * cc + wb][4 * d4];
                        s[rr][cc] += qv[rr].x * pv.x + qv[rr].y * pv.y
                                   + qv[rr].z * pv.z + qv[rr].w * pv.w;
                    }
                }
            }
        }
        #pragma unroll
        for (int rr = 0; rr < 2; ++rr) {
            int il = 2 * ti + rr;
            #pragma unroll
            for (int cc = 0; cc < 4; ++cc) {
                int jl = tj + 16 * cc;
                float v = s[rr][cc] * 0.125f;
                if (t0x >= 0 && (t0x + jl) > (i0 + il)) v = -3e38f;
                Ss[il][jl] = v;
            }
        }
        __syncthreads();
        for (int idx = t; idx < JT * 64; idx += 256) {
            int jl = idx >> 6, d = idx & 63;
            KVs[jl][d] = kv[((size_t)(b * CTXLEN + t0 + jl)) * (2 * D) + D + h * DH + d];
        }
        if (t < AT) {
            int il = t;
            float mo = mrow[il];
            float tmax = -3e38f;
            for (int j = 0; j < JT; ++j) tmax = fmaxf(tmax, Ss[il][j]);
            float mn = fmaxf(mo, tmax);
            float alpha = expf(mo - mn);
            float sum = 0.0f;
            for (int j = 0; j < JT; ++j) {
                float e = expf(Ss[il][j] - mn);
                sum += e;
                int jg = t0 + j;
                float g = (jg < M) ? gates[jg] : 1.0f;
                Ss[il][j] = e * g;
            }
            lrow[il] = lrow[il] * alpha + sum;
            mrow[il] = mn;
            arow[il] = alpha;
        }
        __syncthreads();
        float a0 = arow[2 * ti], a1 = arow[2 * ti + 1];
        #pragma unroll
        for (int dd = 0; dd < 4; ++dd) { O[0][dd] *= a0; O[1][dd] *= a1; }
        #pragma unroll
        for (int jb = 0; jb < 16; ++jb) {
            float4 p0 = *(const float4*)&Ss[2 * ti][4 * jb];
            float4 p1 = *(const float4*)&Ss[2 * ti + 1][4 * jb];
            float4 v0 = *(const float4*)&KVs[4 * jb + 0][4 * tj];
            float4 v1 = *(const float4*)&KVs[4 * jb + 1][4 * tj];
            float4 v2 = *(const float4*)&KVs[4 * jb + 2][4 * tj];
            float4 v3 = *(const float4*)&KVs[4 * jb + 3][4 * tj];
            O[0][0] += p0.x * v0.x + p0.y * v1.x + p0.z * v2.x + p0.w * v3.x;
            O[0][1] += p0.x * v0.y + p0.y * v1.y + p0.z * v2.y + p0.w * v3.y;
            O[0][2] += p0.x * v0.z + p0.y * v1.z + p0.z * v2.z + p0.w * v3.z;
            O[0][3] += p0.x * v0.w + p0.y * v1.w + p0.z * v2.w + p0.w * v3.w;
            O[1][0] += p1.x * v0.x + p1.y * v1.x + p1.z * v2.x + p1.w * v3.x;
            O[1][1] += p1.x * v0.y + p1.y * v1.y + p1.z * v2.y + p1.w * v3.y;
            O[1][2] += p1.x * v0.z + p1.y * v1.z + p1.z * v2.z + p1.w * v3.z;
            O[1][3] += p1.x * v0.w + p1.y * v1.w + p1.z * v2.w + p1.w * v3.w;
        }
    }
    #pragma unroll
    for (int rr = 0; rr < 2; ++rr) {
        int il = 2 * ti + rr;
        float inv = 1.0f / lrow[il];
        float4 r4;
        r4.x = O[rr][0] * inv; r4.y = O[rr][1] * inv;
        r4.z = O[rr][2] * inv; r4.w = O[rr][3] * inv;
        *(float4*)&outp[((size_t)(b * N + i0 + il)) * D + h * DH + 4 * tj] = r4;
    }
}

// ---------------- attention v3 (bf16 path): MFMA QK^T / pos / PV, fp32 kv input ----------------
// AT2=64 q-rows per block, 4 waves, each wave owns one 16-row m-tile.
// Reads FP32 kv (the proven C-path mgemm output) and converts during staging —
// the bf16-kv handoff that poisoned rounds 5-8 is not used.
// Fragment layouts (harness-verified via mgemm): A row=lane&15,k=(lane>>4)*8+e;
// B col=lane&15; C/D col=lane&15, row=(lane>>4)*4+j.
// All bfrag-read LDS arrays use row stride 72 ushorts (144 B, 16B-aligned).
#define AT2 64
#define JSPLIT 2
__global__ __launch_bounds__(256) void attn3_kernel(const float* __restrict__ q,
                                                    const float* __restrict__ kv,
                                                    const float* __restrict__ pos,
                                                    const float* __restrict__ em,
                                                    float* __restrict__ opart,
                                                    float* __restrict__ mlp) {
    __shared__ __align__(16) unsigned short Qb[64][72];    // 9216 B (Q*0.125, bf16)
    __shared__ __align__(16) unsigned short Kb[64][72];    // 9216 B  [j][d]
    __shared__ __align__(16) unsigned short Vt[64][72];    // 9216 B  [d][j] transposed
    __shared__ __align__(16) unsigned short Pb[64][72];    // 9216 B  [r][j]
    __shared__ __align__(16) unsigned short Psb[128][72];  // 18432 B [w][d]
    __shared__ __align__(16) unsigned short Ts[64][88];    // 11264 B per-wave local T (scalar access)
    // total 66560 B -> 2 blocks/CU

    int t = threadIdx.x;
    int bid = blockIdx.x;
    int p   = bid & 1;                   // j-split parity
    int raw = (bid >> 1) & 15;
    int it  = (raw & 1) ? (15 - (raw >> 1)) : (raw >> 1);  // complementary pairing
    int h = (bid >> 5) & 7;
    int b = bid >> 8;
    int i0 = it * AT2;

    int wv = t >> 6;                     // wave id: owns rows wv*16..wv*16+15
    int lane = t & 63;
    int lr = lane & 15;
    int lg = lane >> 4;

    // ---- stage Q (fp32 -> bf16, pre-scaled by DH^-0.5 = 0.125) ----
    for (int idx = t; idx < 64 * 16; idx += 256) {
        int il = idx >> 4, c4 = idx & 15;
        float4 v = *(const float4*)&q[((size_t)(b * N + i0 + il)) * D + h * DH + 4 * c4];
        ushort4 u;
        u.x = f2bits(v.x * 0.125f); u.y = f2bits(v.y * 0.125f);
        u.z = f2bits(v.z * 0.125f); u.w = f2bits(v.w * 0.125f);
        *(ushort4*)&Qb[il][4 * c4] = u;
    }

    ffrag oacc[4] = {};                  // O: col d=lr+16n, row=wv*16+lg*4+jj
    float mo[4] = {-3e38f, -3e38f, -3e38f, -3e38f};
    float lo[4] = {0.0f, 0.0f, 0.0f, 0.0f};

    int ntiles = M / 64 + it + 1;        // 16 mem tiles + (it+1) x tiles
    for (int tile = p; tile < ntiles; tile += JSPLIT) {
        int t0 = tile * 64;
        int t0x = t0 - M;
        __syncthreads();                 // prev tile's LDS reads complete
        // ---- stage K [j][d] and V^T [d][j] from fp32 kv (convert to bf16) ----
        for (int idx = t; idx < 64 * 16; idx += 256) {
            int j = idx >> 4, c4 = idx & 15;
            const float* src = kv + (size_t)(b * CTXLEN + t0 + j) * (2 * D) + h * DH + 4 * c4;
            float4 kq = *(const float4*)src;
            float4 vq = *(const float4*)(src + D);
            ushort4 ku;
            ku.x = f2bits(kq.x); ku.y = f2bits(kq.y); ku.z = f2bits(kq.z); ku.w = f2bits(kq.w);
            *(ushort4*)&Kb[j][4 * c4] = ku;
            Vt[4 * c4 + 0][j] = f2bits(vq.x);
            Vt[4 * c4 + 1][j] = f2bits(vq.y);
            Vt[4 * c4 + 2][j] = f2bits(vq.z);
            Vt[4 * c4 + 3][j] = f2bits(vq.w);
        }
        // ---- stage pos window [w][d] (bf16) for x-tiles ----
        if (t0x >= 0) {
            int r0 = N - 1 - (i0 + AT2 - 1) + t0x;
            for (int idx = t; idx < 128 * 8; idx += 256) {
                int w = idx >> 3, c8 = idx & 7;
                int r = r0 + w; r = r > (N - 1) ? (N - 1) : r;
                const float* pp = &pos[(size_t)r * DH + 8 * c8];
                float4 a = *(const float4*)pp;
                float4 bb = *(const float4*)(pp + 4);
                ushort4 u0, u1;
                u0.x = f2bits(a.x);  u0.y = f2bits(a.y);  u0.z = f2bits(a.z);  u0.w = f2bits(a.w);
                u1.x = f2bits(bb.x); u1.y = f2bits(bb.y); u1.z = f2bits(bb.z); u1.w = f2bits(bb.w);
                *(ushort4*)&Psb[w][8 * c8]     = u0;
                *(ushort4*)&Psb[w][8 * c8 + 4] = u1;
            }
        }
        __syncthreads();                 // staging done
        // ---- S = Q K^T via MFMA: wave computes S[16][64] ----
        bfrag aq[2];
        #pragma unroll
        for (int ks = 0; ks < 2; ++ks)
            aq[ks] = *(const bfrag*)&Qb[wv * 16 + lr][ks * 32 + lg * 8];
        ffrag sacc[4] = {};
        #pragma unroll
        for (int ks = 0; ks < 2; ++ks)
            #pragma unroll
            for (int n = 0; n < 4; ++n) {
                bfrag bk = *(const bfrag*)&Kb[n * 16 + lr][ks * 32 + lg * 8];
                sacc[n] = __builtin_amdgcn_mfma_f32_16x16x32_bf16(aq[ks], bk, sacc[n], 0, 0, 0);
            }
        // ---- pos skew via MFMA (x-tiles): T[16][80] then diagonal extract ----
        if (t0x >= 0) {
            int base = 48 - 16 * wv;     // w = w' + base, w' = jl + 15 - rl
            ffrag tacc[5] = {};
            #pragma unroll
            for (int ks = 0; ks < 2; ++ks)
                #pragma unroll
                for (int n5 = 0; n5 < 5; ++n5) {
                    bfrag bp = *(const bfrag*)&Psb[base + n5 * 16 + lr][ks * 32 + lg * 8];
                    tacc[n5] = __builtin_amdgcn_mfma_f32_16x16x32_bf16(aq[ks], bp, tacc[n5], 0, 0, 0);
                }
            #pragma unroll
            for (int n5 = 0; n5 < 5; ++n5)
                #pragma unroll
                for (int jj = 0; jj < 4; ++jj)
                    Ts[wv * 16 + lg * 4 + jj][n5 * 16 + lr] = f2bits(tacc[n5][jj]);
            // same-wave RAW on LDS: DS ops complete in order within a wave
            #pragma unroll
            for (int jj = 0; jj < 4; ++jj) {
                int rl = lg * 4 + jj;
                #pragma unroll
                for (int n = 0; n < 4; ++n) {
                    int wp = (lr + 16 * n) + 15 - rl;
                    sacc[n][jj] += us2f(Ts[wv * 16 + rl][wp]);
                }
            }
        }
        // ---- gates ----
        float gate[4];
        #pragma unroll
        for (int n = 0; n < 4; ++n) {
            int jg = t0 + lr + 16 * n;
            gate[n] = (jg < M) ? em[b * M + jg] : 1.0f;
        }
        // ---- causal mask ----
        if (t0x >= 0) {
            #pragma unroll
            for (int jj = 0; jj < 4; ++jj) {
                int ig = i0 + wv * 16 + lg * 4 + jj;
                #pragma unroll
                for (int n = 0; n < 4; ++n)
                    if (t0x + lr + 16 * n > ig) sacc[n][jj] = -3e38f;
            }
        }
        // ---- online softmax (rows live across the 16 consecutive lanes of each lg group) ----
        #pragma unroll
        for (int jj = 0; jj < 4; ++jj) {
            float tmax = fmaxf(fmaxf(sacc[0][jj], sacc[1][jj]), fmaxf(sacc[2][jj], sacc[3][jj]));
            tmax = fmaxf(tmax, __shfl_xor(tmax, 1, 16));
            tmax = fmaxf(tmax, __shfl_xor(tmax, 2, 16));
            tmax = fmaxf(tmax, __shfl_xor(tmax, 4, 16));
            tmax = fmaxf(tmax, __shfl_xor(tmax, 8, 16));
            float mn = fmaxf(mo[jj], tmax);
            float al = __expf(mo[jj] - mn);
            mo[jj] = mn;
            float e0 = __expf(sacc[0][jj] - mn);
            float e1 = __expf(sacc[1][jj] - mn);
            float e2 = __expf(sacc[2][jj] - mn);
            float e3 = __expf(sacc[3][jj] - mn);
            float sum = e0 + e1 + e2 + e3;
            sum += __shfl_xor(sum, 1, 16);
            sum += __shfl_xor(sum, 2, 16);
            sum += __shfl_xor(sum, 4, 16);
            sum += __shfl_xor(sum, 8, 16);
            lo[jj] = lo[jj] * al + sum;
            #pragma unroll
            for (int n = 0; n < 4; ++n) oacc[n][jj] *= al;
            int r = wv * 16 + lg * 4 + jj;
            Pb[r][lr]      = f2bits(e0 * gate[0]);
            Pb[r][lr + 16] = f2bits(e1 * gate[1]);
            Pb[r][lr + 32] = f2bits(e2 * gate[2]);
            Pb[r][lr + 48] = f2bits(e3 * gate[3]);
        }
        // ---- PV via MFMA (same-wave LDS RAW on Pb) ----
        #pragma unroll
        for (int ks = 0; ks < 2; ++ks) {
            bfrag ap = *(const bfrag*)&Pb[wv * 16 + lr][ks * 32 + lg * 8];
            #pragma unroll
            for (int n = 0; n < 4; ++n) {
                bfrag bv = *(const bfrag*)&Vt[n * 16 + lr][ks * 32 + lg * 8];
                oacc[n] = __builtin_amdgcn_mfma_f32_16x16x32_bf16(ap, bv, oacc[n], 0, 0, 0);
            }
        }
    }
    // ---- write unnormalized partials + (m,l) ----
    size_t ob = ((size_t)((p * BATCH + b) * H + h) * N + i0) * DH;
    #pragma unroll
    for (int jj = 0; jj < 4; ++jj) {
        int rl = wv * 16 + lg * 4 + jj;
        #pragma unroll
        for (int n = 0; n < 4; ++n)
            opart[ob + (size_t)rl * DH + lr + 16 * n] = oacc[n][jj];
        if (lr == 0) {
            size_t mlIdx = (((size_t)(p * BATCH + b) * H + h) * N + i0 + rl) * 2;
            mlp[mlIdx]     = mo[jj];
            mlp[mlIdx + 1] = lo[jj];
        }
    }
}

// ---------------- combine j-split partials ----------------
__global__ __launch_bounds__(256) void attn_combine_kernel(const float* __restrict__ opart,
                                                           const float* __restrict__ mlp,
                                                           float* __restrict__ aout) {
    int row = blockIdx.x;            // b*N + i
    int b = row >> 10;
    int i = row & (N - 1);
    for (int d = threadIdx.x; d < D; d += 256) {
        int h = d >> 6, dd = d & 63;
        size_t s0 = ((size_t)(b * H + h) * N + i);
        size_t s1 = ((size_t)((BATCH + b) * H + h) * N + i);
        float m0 = mlp[s0 * 2], l0 = mlp[s0 * 2 + 1];
        float m1 = mlp[s1 * 2], l1 = mlp[s1 * 2 + 1];
        float m = fmaxf(m0, m1);
        float w0 = __expf(m0 - m), w1 = __expf(m1 - m);
        float denom = l0 * w0 + l1 * w1;
        aout[(size_t)row * D + d] = (opart[s0 * DH + dd] * w0 + opart[s1 * DH + dd] * w1) / denom;
    }
}

// ---------------- final layernorm ----------------
__global__ __launch_bounds__(256) void ln_kernel(const float* __restrict__ x,
                                                 const void* __restrict__ g,
                                                 const void* __restrict__ bta,
                                                 float* __restrict__ y,
                                                 const int* __restrict__ dflag) {
    int f = *dflag;
    int row = blockIdx.x;
    const float* xr = x + (size_t)row * D;
    __shared__ float red[4];
    int lane = threadIdx.x & 63, wv = threadIdx.x >> 6;
    float s = 0.0f;
    for (int d = threadIdx.x; d < D; d += 256) s += xr[d];
    #pragma unroll
    for (int off = 32; off > 0; off >>= 1) s += __shfl_xor(s, off, 64);
    if (lane == 0) red[wv] = s;
    __syncthreads();
    float mu = (red[0] + red[1] + red[2] + red[3]) * (1.0f / D);
    __syncthreads();
    float v = 0.0f;
    for (int d = threadIdx.x; d < D; d += 256) { float tt = xr[d] - mu; v += tt * tt; }
    #pragma unroll
    for (int off = 32; off > 0; off >>= 1) v += __shfl_xor(v, off, 64);
    if (lane == 0) red[wv] = v;
    __syncthreads();
    float var = (red[0] + red[1] + red[2] + red[3]) * (1.0f / D);
    float rstd = 1.0f / sqrtf(var + 1e-5f);
    for (int d = threadIdx.x; d < D; d += 256)
        y[(size_t)row * D + d] = (xr[d] - mu) * rstd * ldf(g, d, f) + ldf(bta, d, f);
}

// ---------------- aux write ----------------
__global__ void write_aux_kernel(const float* __restrict__ aux, void* __restrict__ out,
                                 const int* __restrict__ dflag) {
    int f = *dflag;
    if (threadIdx.x < BATCH)
        stf(out, (size_t)ROWS * V + threadIdx.x, f, aux[threadIdx.x]);
}

extern "C" void kernel_launch(void* const* d_in, const int* in_sizes, int n_in,
                              void* d_out, int out_size, void* d_ws, size_t ws_size,
                              hipStream_t stream) {
    (void)n_in; (void)out_size; (void)ws_size;
    const int*  tokens  = (const int*)d_in[0];
    const void* mems    = d_in[1];
    const int*  times   = (const int*)d_in[2];
    const void* tok_emb = d_in[3];
    const void* Wq   = d_in[4];
    const void* bq   = d_in[5];
    const void* Wkv  = d_in[6];
    const void* bkv  = d_in[7];
    const void* Wo   = d_in[8];
    const void* bo   = d_in[9];
    const void* Wpos = d_in[10];
    const void* bpos = d_in[11];
    const void* Wexp = d_in[12];
    const void* bexp = d_in[13];
    const void* W1   = d_in[14];
    const void* b1   = d_in[15];
    const void* W2   = d_in[16];
    const void* b2v  = d_in[17];
    const void* ln_g = d_in[18];
    const void* ln_b = d_in[19];
    const void* Whead= d_in[20];

    float* ws  = (float*)d_ws;
    float* x    = ws;                            // ROWS*D
    float* pe   = x    + (size_t)ROWS * D;       // N*D
    float* ctx  = pe   + (size_t)N * D;          // CROWS*D   (y, opart alias)
    float* kv   = ctx  + (size_t)CROWS * D;      // CROWS*2D  (h1 aliases)
    float* q    = kv   + (size_t)CROWS * 2 * D;  // ROWS*D
    float* pos  = q    + (size_t)ROWS * D;       // N*DH
    float* em   = pos  + (size_t)N * DH;         // B*M
    float* aout = em   + (size_t)BATCH * M;      // ROWS*D
    float* aux  = aout + (size_t)ROWS * D;       // 2 floats + flag
    int*   flag = (int*)(aux + 2);
    float* mlp  = aux + 16;                      // JSPLIT*B*H*N*2 = 65,536 floats
    float* h1   = kv;   // alias
    float* y    = ctx;  // alias
    float* opart = ctx; // alias: CROWS*D == JSPLIT*B*H*N*DH floats; ctx dead during attn

    // Host-side dtype guess from staged byte size of tok_emb (V*D elems).
    int hf32 = (in_sizes && in_sizes[3] >= (int)(V * (size_t)D * 3)) ? 1 : 0;

    detect_kernel<<<1, 256, 0, stream>>>(tok_emb, flag, aux);
    embed_kernel<<<ROWS, 256, 0, stream>>>(tokens, tok_emb, x, flag);
    pe_kernel<<<N, 256, 0, stream>>>(pe);

    for (int l = 0; l < DEPTH; ++l) {
        expire_kernel<<<(BATCH * M) / 4, 256, 0, stream>>>(
            mems, (size_t)l * BATCH * M * D, times + (size_t)l * BATCH * M,
            Wexp, (size_t)l * D, bexp, (size_t)l, em, aux, flag);
        ctx_kernel<<<(BATCH * CTXLEN * D) / 256, 256, 0, stream>>>(
            mems, (size_t)l * BATCH * M * D, x, ctx, flag);
        if (hf32) {
            gemm_kernel<<<dim3(D / BN, ROWS / BM), 256, 0, stream>>>(
                ROWS, D, D, x, Wq, (size_t)l * D * D, bq, (size_t)l * D, q, nullptr, 0, flag);
            gemm_kernel<<<dim3(2 * D / BN, CROWS / BM), 256, 0, stream>>>(
                CROWS, 2 * D, D, ctx, Wkv, (size_t)l * D * 2 * D, bkv, (size_t)l * 2 * D, kv, nullptr, 0, flag);
        } else {
            mgemm_kernel<<<dim3(ROWS / 128, D / 128), 256, 0, stream>>>(
                ROWS, D, D, x, Wq, (size_t)l * D * D, bq, (size_t)l * D, q, nullptr, 0, flag);
            mgemm_kernel<<<dim3(CROWS / 128, 2 * D / 128), 256, 0, stream>>>(
                CROWS, 2 * D, D, ctx, Wkv, (size_t)l * D * 2 * D, bkv, (size_t)l * 2 * D, kv, nullptr, 0, flag);
        }
        gemm_kernel<<<dim3(DH / BN, N / BM), 256, 0, stream>>>(
            N, DH, D, pe, Wpos, (size_t)l * D * DH, bpos, (size_t)l * DH, pos, nullptr, 0, flag);
        if (hf32) {
            attn_kernel<<<BATCH * H * (N / AT), 256, 0, stream>>>(q, kv, pos, em, aout);
        } else {
            attn3_kernel<<<BATCH * H * (N / AT2) * JSPLIT, 256, 0, stream>>>(
                q, kv, pos, em, opart, mlp);
            attn_combine_kernel<<<ROWS, 256, 0, stream>>>(opart, mlp, aout);
        }
        if (hf32) {
            gemm_kernel<<<dim3(D / BN, ROWS / BM), 256, 0, stream>>>(
                ROWS, D, D, aout, Wo, (size_t)l * D * D, bo, (size_t)l * D, x, nullptr, 1, flag);
            gemm_kernel<<<dim3(4 * D / BN, ROWS / BM), 256, 0, stream>>>(
                ROWS, 4 * D, D, x, W1, (size_t)l * D * 4 * D, b1, (size_t)l * 4 * D, h1, nullptr, 2, flag);
            gemm_kernel<<<dim3(D / BN, ROWS / BM), 256, 0, stream>>>(
                ROWS, D, 4 * D, h1, W2, (size_t)l * 4 * D * D, b2v, (size_t)l * D, x, nullptr, 1, flag);
        } else {
            mgemm_kernel<<<dim3(ROWS / 128, D / 128), 256, 0, stream>>>(
                ROWS, D, D, aout, Wo, (size_t)l * D * D, bo, (size_t)l * D, x, nullptr, 1, flag);
            mgemm_kernel<<<dim3(ROWS / 128, 4 * D / 128), 256, 0, stream>>>(
                ROWS, 4 * D, D, x, W1, (size_t)l * D * 4 * D, b1, (size_t)l * 4 * D, h1, nullptr, 2, flag);
            mgemm_kernel<<<dim3(ROWS / 128, D / 128), 256, 0, stream>>>(
                ROWS, D, 4 * D, h1, W2, (size_t)l * 4 * D * D, b2v, (size_t)l * D, x, nullptr, 1, flag);
        }
    }

    ln_kernel<<<ROWS, 256, 0, stream>>>(x, ln_g, ln_b, y, flag);
    if (hf32) {
        gemm_kernel<<<dim3(V / BN, ROWS / BM), 256, 0, stream>>>(
            ROWS, V, D, y, Whead, 0, nullptr, 0, nullptr, d_out, 0, flag);
    } else {
        mgemm_kernel<<<dim3(ROWS / 128, V / 128), 256, 0, stream>>>(
            ROWS, V, D, y, Whead, 0, nullptr, 0, nullptr, d_out, 0, flag);
    }
    write_aux_kernel<<<1, 64, 0, stream>>>(aux, d_out, flag);
}